// Round 3
// baseline (4649.927 us; speedup 1.0000x reference)
//
#include <hip/hip_runtime.h>

#define BB 8
#define CC 64
#define TT 128
#define PP (TT*TT)
#define C3 192
#define CTILE 16
#define GT 8

// ---------------------------------------------------------------------------
// prep: combined down-conv weights (ps4/il2/2x2-stride2 chain folds into four
// per-pixel 1x1 convs) + transposed w_hc for coalesced lane access.
// ---------------------------------------------------------------------------
__global__ void k_prep(const float* __restrict__ w_down, const float* __restrict__ w_hc,
                       float* __restrict__ wc, float* __restrict__ whcT){
  int i = blockIdx.x*256 + threadIdx.x;
  if (i < 128*128*9){
    // w_hc[wo][wi][dh][dc] -> whcT[(dh*3+dc)][wi][wo]
    int wo = i / 1152;
    int r  = i % 1152;
    int wi = r / 9;
    int t  = r % 9;
    whcT[(t*128 + wi)*128 + wo] = w_hc[i];
  }
  if (i < 64*64){
    int o = i >> 6, k = i & 63;
    const float* wd = w_down + o*512 + k*8;   // [o][2k..2k+1][dy][dx]
    float a00=wd[0], a01=wd[1], a10=wd[2], a11=wd[3];
    float b00=wd[4], b01=wd[5], b10=wd[6], b11=wd[7];
    wc[0*4096 + i] = a00 + b11;  // Wx
    wc[1*4096 + i] = a01 + b10;  // Whw
    wc[2*4096 + i] = a10 + b01;  // Wcw
    wc[3*4096 + i] = a11 + b00;  // Whc
  }
}

// ---------------------------------------------------------------------------
// fused 1x1 expand + depthwise 3x3 -> gate maps g[b,192,h,w]
// block: 256 thr, grid (TT/GT, 192, nb). 10-row fp32 slab of the 1x1 result
// in LDS, then dw 3x3 on 8 rows. 10/8 recompute vs materializing t (96 MB).
// ---------------------------------------------------------------------------
__global__ void k_gates(const float* __restrict__ x, const float* __restrict__ w_hwc,
                        const float* __restrict__ b_hwc, const float* __restrict__ w_dw,
                        const float* __restrict__ b_dw, float* __restrict__ g){
  int b = blockIdx.z, ch = blockIdx.y, h0 = blockIdx.x*GT;
  __shared__ float ts[GT+2][TT];
  __shared__ float wf[64];
  if (threadIdx.x < 64) wf[threadIdx.x] = w_hwc[ch*64 + threadIdx.x];
  __syncthreads();
  float bias1 = b_hwc[ch];
  for (int idx = threadIdx.x; idx < (GT+2)*TT; idx += 256){
    int r = idx / TT, w = idx % TT;
    int hh = h0 - 1 + r;
    float acc = 0.f;
    if (hh >= 0 && hh < TT){
      const float* xp = x + b*CC*PP + hh*TT + w;
      acc = bias1;
      #pragma unroll 8
      for (int ic=0; ic<64; ++ic) acc += wf[ic]*xp[ic*PP];
    }
    ts[r][w] = acc;
  }
  __syncthreads();
  const float* wd = w_dw + ch*9;
  float w00=wd[0],w01=wd[1],w02=wd[2],
        w10=wd[3],w11=wd[4],w12=wd[5],
        w20=wd[6],w21=wd[7],w22=wd[8];
  float bias2 = b_dw[ch];
  for (int idx = threadIdx.x; idx < GT*TT; idx += 256){
    int r = idx / TT, w = idx % TT;
    float acc = bias2;
    float a0 = (w>=1)? ts[r  ][w-1]:0.f, b0 = ts[r  ][w], c0 = (w<=126)? ts[r  ][w+1]:0.f;
    float a1 = (w>=1)? ts[r+1][w-1]:0.f, b1 = ts[r+1][w], c1 = (w<=126)? ts[r+1][w+1]:0.f;
    float a2 = (w>=1)? ts[r+2][w-1]:0.f, b2 = ts[r+2][w], c2 = (w<=126)? ts[r+2][w+1]:0.f;
    acc += w00*a0+w01*b0+w02*c0 + w10*a1+w11*b1+w12*c1 + w20*a2+w21*b2+w22*c2;
    g[(b*C3+ch)*PP + (h0+r)*TT + w] = acc;
  }
}

// ---------------------------------------------------------------------------
// standard 64->64 3x3 conv, block=(w:128), grid=(h, oc, nb)
// mode 0: y = lrelu(conv) * gate[b, goff+oc]      (x_hw)
// mode 1: y = lrelu(conv)                          (l1)
// mode 2: y = res + lrelu(conv)                    (l2 + final residual)
// ---------------------------------------------------------------------------
__global__ void k_conv3x3(const float* __restrict__ in, const float* __restrict__ w,
                          const float* __restrict__ bias, const float* __restrict__ gate,
                          int goff, const float* __restrict__ res,
                          float* __restrict__ y, int mode){
  int b = blockIdx.z, oc = blockIdx.y, h = blockIdx.x;
  int wv = threadIdx.x;
  float acc = bias[oc];
  const float* wb = w + oc*64*9;
  #pragma unroll 4
  for (int ic=0; ic<64; ++ic){
    const float* xin = in + (b*CC+ic)*PP;
    const float* wr = wb + ic*9;
    #pragma unroll
    for (int dh=0; dh<3; ++dh){
      int hh = h + dh - 1;
      if (hh < 0 || hh >= TT) continue;
      const float* row = xin + hh*TT;
      float x0 = (wv >= 1)   ? row[wv-1] : 0.f;
      float x1 = row[wv];
      float x2 = (wv <= 126) ? row[wv+1] : 0.f;
      acc += wr[dh*3+0]*x0 + wr[dh*3+1]*x1 + wr[dh*3+2]*x2;
    }
  }
  float v = acc > 0.f ? acc : 0.1f*acc;
  int pi = h*TT + wv;
  float outv;
  if (mode == 0)      outv = v * gate[(b*C3 + goff + oc)*PP + pi];
  else if (mode == 1) outv = v;
  else                outv = v + res[(b*CC+oc)*PP + pi];
  y[(b*CC+oc)*PP + pi] = outv;
}

// ---------------------------------------------------------------------------
// x_cw: conv over the H dimension as channels (x transposed (0,2,1,3)), done
// directly in original layout. out[b,c,ho,w], block=(w:128), grid=(ho,c,nb)
// ---------------------------------------------------------------------------
__global__ void k_convcw(const float* __restrict__ x, const float* __restrict__ w,
                         const float* __restrict__ bias, const float* __restrict__ g,
                         float* __restrict__ y){
  int b = blockIdx.z, c = blockIdx.y, ho = blockIdx.x;
  int wv = threadIdx.x;
  float acc = bias[ho];
  #pragma unroll
  for (int dc=0; dc<3; ++dc){
    int cc = c + dc - 1;
    if (cc < 0 || cc >= CC) continue;
    const float* xin = x + (b*CC+cc)*PP;
    const float* wb = w + (ho*TT)*9 + dc*3;
    for (int hi=0; hi<TT; ++hi){
      const float* row = xin + hi*TT;
      const float* wr = wb + hi*9;
      float x0 = (wv >= 1)   ? row[wv-1] : 0.f;
      float x1 = row[wv];
      float x2 = (wv <= 126) ? row[wv+1] : 0.f;
      acc += wr[0]*x0 + wr[1]*x1 + wr[2]*x2;
    }
  }
  float v = acc > 0.f ? acc : 0.1f*acc;
  int pi = ho*TT + wv;
  v *= g[(b*C3 + 64 + c)*PP + pi];
  y[((b*CC+c)*TT+ho)*TT + wv] = v;
}

// ---------------------------------------------------------------------------
// x_hc: conv over the W dimension as channels (x transposed (0,3,2,1)).
// out[b,c,h,wo], block=(wo:128), 16 c-accumulators per lane, x slab in LDS.
// grid=(h, c/16, nb)
// ---------------------------------------------------------------------------
__global__ void k_convhc(const float* __restrict__ x, const float* __restrict__ whcT,
                         const float* __restrict__ bias, const float* __restrict__ g,
                         float* __restrict__ y){
  int b = blockIdx.z, ct = blockIdx.y, h = blockIdx.x;
  int wo = threadIdx.x;
  __shared__ float xs[3][CTILE+2][TT];
  for (int idx = threadIdx.x; idx < 3*(CTILE+2)*TT; idx += 128){
    int dh = idx / ((CTILE+2)*TT);
    int r  = idx % ((CTILE+2)*TT);
    int ci = r / TT;
    int wi = r % TT;
    int c  = ct*CTILE + ci - 1;
    int hh = h + dh - 1;
    float v = 0.f;
    if (c >= 0 && c < CC && hh >= 0 && hh < TT)
      v = x[((b*CC+c)*TT+hh)*TT + wi];
    ((float*)xs)[idx] = v;
  }
  __syncthreads();
  float bias_v = bias[wo];
  float acc[CTILE];
  #pragma unroll
  for (int j=0;j<CTILE;++j) acc[j]=bias_v;
  #pragma unroll
  for (int dh=0; dh<3; ++dh){
    #pragma unroll
    for (int dc=0; dc<3; ++dc){
      const float* wp = whcT + (dh*3+dc)*TT*TT + wo;
      for (int wi=0; wi<TT; ++wi){
        float wvv = wp[wi*TT];
        const float* xr = &xs[dh][dc][wi];   // j-stride = TT floats
        #pragma unroll
        for (int j=0;j<CTILE;++j)
          acc[j] += wvv * xr[j*TT];
      }
    }
  }
  int pi = h*TT + wo;
  #pragma unroll
  for (int j=0;j<CTILE;++j){
    int c = ct*CTILE + j;
    float v = acc[j] > 0.f ? acc[j] : 0.1f*acc[j];
    v *= g[(b*C3 + 128 + c)*PP + pi];
    y[((b*CC+c)*TT+h)*TT + wo] = v;
  }
}

// ---------------------------------------------------------------------------
// folded down-conv (four 1x1s) + residual: outb[b,o,p]
// ---------------------------------------------------------------------------
__global__ void k_down(const float* __restrict__ x, const float* __restrict__ xhw,
                       const float* __restrict__ xcw, const float* __restrict__ xhc,
                       const float* __restrict__ wc, const float* __restrict__ bias,
                       float* __restrict__ outb){
  int b = blockIdx.z, o = blockIdx.y;
  int p = blockIdx.x*256 + threadIdx.x;
  const float* Wx  = wc + 0*4096 + o*64;
  const float* Whw = wc + 1*4096 + o*64;
  const float* Wcw = wc + 2*4096 + o*64;
  const float* Whc = wc + 3*4096 + o*64;
  float acc = bias[o];
  int base = b*CC*PP + p;
  #pragma unroll 4
  for (int k=0;k<64;++k){
    int off = base + k*PP;
    acc += Wx[k]*x[off] + Whw[k]*xhw[off]
         + Wcw[k]*xcw[off] + Whc[k]*xhc[off];
  }
  acc += x[base + o*PP];
  outb[(b*CC+o)*PP + p] = acc;
}

// ---------------------------------------------------------------------------
extern "C" void kernel_launch(void* const* d_in, const int* in_sizes, int n_in,
                              void* d_out, int out_size, void* d_ws, size_t ws_size,
                              hipStream_t stream) {
  const float* x      = (const float*)d_in[0];
  const float* w_hwc  = (const float*)d_in[1];
  const float* b_hwc  = (const float*)d_in[2];
  const float* w_dw   = (const float*)d_in[3];
  const float* b_dw   = (const float*)d_in[4];
  const float* w_hw   = (const float*)d_in[5];
  const float* b_hw   = (const float*)d_in[6];
  const float* w_cw   = (const float*)d_in[7];
  const float* b_cw   = (const float*)d_in[8];
  const float* w_hc   = (const float*)d_in[9];
  const float* b_hc   = (const float*)d_in[10];
  const float* w_down = (const float*)d_in[11];
  const float* b_down = (const float*)d_in[12];
  const float* w_l1   = (const float*)d_in[13];
  const float* b_l1   = (const float*)d_in[14];
  const float* w_l2   = (const float*)d_in[15];
  const float* b_l2   = (const float*)d_in[16];
  float* out = (float*)d_out;

  char* ws = (char*)d_ws;
  float* wc   = (float*)(ws + 0);        // 64 KB
  float* whcT = (float*)(ws + 65536);    // 576 KB -> ends 655360

  k_prep<<<576, 256, 0, stream>>>(w_down, w_hc, wc, whcT);

  if (ws_size >= 202375168ull) {
    // ---- full-batch path (193 MB peak, fp32) ----
    float* g    = (float*)(ws + 1048576);     // 96 MB -> 101711872
    float* xhw  = (float*)(ws + 101711872);   // 32 MB
    float* xcw  = (float*)(ws + 135266304);   // 32 MB
    float* xhc  = (float*)(ws + 168820736);   // 32 MB -> 202375168
    float* o1   = (float*)(ws + 1048576);     // aliases g (dead by then)
    float* outb = out;                        // d_out as scratch (dead after l1)

    k_gates<<<dim3(TT/GT, C3, BB), 256, 0, stream>>>(x, w_hwc, b_hwc, w_dw, b_dw, g);
    k_conv3x3<<<dim3(TT, CC, BB), 128, 0, stream>>>(x, w_hw, b_hw, g, 0, nullptr, xhw, 0);
    k_convcw<<<dim3(TT, CC, BB), 128, 0, stream>>>(x, w_cw, b_cw, g, xcw);
    k_convhc<<<dim3(TT, CC/CTILE, BB), 128, 0, stream>>>(x, whcT, b_hc, g, xhc);
    k_down<<<dim3(PP/256, CC, BB), 256, 0, stream>>>(x, xhw, xcw, xhc, wc, b_down, outb);
    k_conv3x3<<<dim3(TT, CC, BB), 128, 0, stream>>>(outb, w_l1, b_l1, nullptr, 0, nullptr, o1, 1);
    k_conv3x3<<<dim3(TT, CC, BB), 128, 0, stream>>>(o1, w_l2, b_l2, nullptr, 0, x, out, 2);
  } else {
    // ---- per-batch path (28.7 MB peak, fp32) ----
    char* P = ws + 655360;
    float* g_b   = (float*)(P);               // 12 MB
    float* xhw_b = (float*)(P + 12582912);    // 4 MB
    float* xcw_b = (float*)(P + 16777216);    // 4 MB
    float* xhc_b = (float*)(P + 20971520);    // 4 MB
    float* o1_b  = (float*)(P + 25165824);    // 4 MB -> total 30015488
    for (int b = 0; b < BB; ++b) {
      const float* xb = x + (size_t)b*CC*PP;
      float* outb_b = out + (size_t)b*CC*PP;
      k_gates<<<dim3(TT/GT, C3, 1), 256, 0, stream>>>(xb, w_hwc, b_hwc, w_dw, b_dw, g_b);
      k_conv3x3<<<dim3(TT, CC, 1), 128, 0, stream>>>(xb, w_hw, b_hw, g_b, 0, nullptr, xhw_b, 0);
      k_convcw<<<dim3(TT, CC, 1), 128, 0, stream>>>(xb, w_cw, b_cw, g_b, xcw_b);
      k_convhc<<<dim3(TT, CC/CTILE, 1), 128, 0, stream>>>(xb, whcT, b_hc, g_b, xhc_b);
      k_down<<<dim3(PP/256, CC, 1), 256, 0, stream>>>(xb, xhw_b, xcw_b, xhc_b, wc, b_down, outb_b);
      k_conv3x3<<<dim3(TT, CC, 1), 128, 0, stream>>>(outb_b, w_l1, b_l1, nullptr, 0, nullptr, o1_b, 1);
      k_conv3x3<<<dim3(TT, CC, 1), 128, 0, stream>>>(o1_b, w_l2, b_l2, nullptr, 0, xb, outb_b, 2);
    }
  }
}

// Round 4
// 2678.128 us; speedup vs baseline: 1.7363x; 1.7363x over previous
//
#include <hip/hip_runtime.h>
#include <hip/hip_bf16.h>

#define BB 8
#define CC 64
#define TT 128
#define PP (TT*TT)
#define C3 192

typedef __hip_bfloat16 bf16;
__device__ __forceinline__ float b2f(bf16 v){ return __bfloat162float(v); }
__device__ __forceinline__ bf16 f2b(float v){ return __float2bfloat16(v); }

// ---------------------------------------------------------------------------
// prep: all weight transposes (for wave-uniform scalar weight loads), the
// folded down-conv weights, and a 128-float zero row for OOB row pointers.
// ---------------------------------------------------------------------------
__global__ void k_prep(const float* __restrict__ w_down, const float* __restrict__ w_hc,
                       const float* __restrict__ w_cw,  const float* __restrict__ w_hwc,
                       const float* __restrict__ w_hw,  const float* __restrict__ w_l1,
                       const float* __restrict__ w_l2,
                       float* __restrict__ wcT,  float* __restrict__ whcT,
                       float* __restrict__ wcwT, float* __restrict__ w1T,
                       float* __restrict__ whwT, float* __restrict__ wl1T,
                       float* __restrict__ wl2T, float* __restrict__ zrow){
  int i = blockIdx.x*256 + threadIdx.x;
  if (i < 128*128*9){
    int a  = i / 1152;          // wo (hc) / ho (cw)
    int r  = i % 1152;
    int m  = r / 9;             // wi (hc) / hi (cw)
    int t  = r % 9;
    // w_hc[wo][wi][dh][dc] -> whcT[((dh*3+dc)*128+wi)*128 + wo]
    whcT[(t*128 + m)*128 + a] = w_hc[i];
    // w_cw[ho][hi][dc][dw] -> wcwT[((hi*3+dc)*3+dw)*128 + ho]
    wcwT[(m*9 + t)*128 + a] = w_cw[i];
  }
  if (i < 12288){               // w_hwc[oc192][ic64] -> w1T[ic*192+oc]
    int oc = i / 64, ic = i % 64;
    w1T[ic*192 + oc] = w_hwc[i];
  }
  if (i < 36864){               // w[oc64][ic64][3][3] -> wT[(ic*9+t)*64+oc]
    int oc = i / 576; int r = i % 576; int ic = r / 9; int t = r % 9;
    whwT[(ic*9+t)*64 + oc] = w_hw[i];
    wl1T[(ic*9+t)*64 + oc] = w_l1[i];
    wl2T[(ic*9+t)*64 + oc] = w_l2[i];
  }
  if (i < 4096){                // folded down weights, [r][k][o] layout
    int o = i >> 6, k = i & 63;
    const float* wd = w_down + o*512 + k*8;
    wcT[0*4096 + k*64 + o] = wd[0] + wd[7];  // X
    wcT[1*4096 + k*64 + o] = wd[1] + wd[6];  // HW
    wcT[2*4096 + k*64 + o] = wd[2] + wd[5];  // CW
    wcT[3*4096 + k*64 + o] = wd[3] + wd[4];  // HC
  }
  if (i < 128) zrow[i] = 0.f;
}

// ---------------------------------------------------------------------------
// 1x1 expand, 16-oc register tile: t[ch,p] for one batch.
// grid (PP/256, 192/16), block 256.
// ---------------------------------------------------------------------------
__global__ void k_1x1(const float* __restrict__ xb, const float* __restrict__ w1T,
                      const float* __restrict__ b_hwc, float* __restrict__ t){
  int p  = blockIdx.x*256 + threadIdx.x;
  int c0 = blockIdx.y*16;
  float acc[16];
  #pragma unroll
  for (int i=0;i<16;++i) acc[i] = b_hwc[c0+i];
  const float* xp = xb + p;
  for (int ic=0; ic<64; ++ic){
    float xv = xp[ic*PP];
    const float* wr = w1T + ic*192 + c0;
    #pragma unroll
    for (int i=0;i<16;++i) acc[i] += wr[i]*xv;
  }
  #pragma unroll
  for (int i=0;i<16;++i) t[(c0+i)*PP + p] = acc[i];
}

// ---------------------------------------------------------------------------
// depthwise 3x3 on t -> bf16 gates for one batch. grid (PP/256, 192), block 256.
// ---------------------------------------------------------------------------
__global__ void k_dw(const float* __restrict__ t, const float* __restrict__ w_dw,
                     const float* __restrict__ b_dw, bf16* __restrict__ gb){
  int ch = blockIdx.y;
  int p  = blockIdx.x*256 + threadIdx.x;
  int h = p >> 7, w = p & 127;
  const float* tp = t + ch*PP;
  const float* wd = w_dw + ch*9;
  float acc = b_dw[ch];
  #pragma unroll
  for (int dh=0; dh<3; ++dh){
    int hh = h + dh - 1;
    if (hh < 0 || hh >= TT) continue;
    const float* row = tp + hh*TT;
    float x0 = (w>=1)  ? row[w-1] : 0.f;
    float x1 = row[w];
    float x2 = (w<=126)? row[w+1] : 0.f;
    acc += wd[dh*3+0]*x0 + wd[dh*3+1]*x1 + wd[dh*3+2]*x2;
  }
  gb[ch*PP + p] = f2b(acc);
}

// ---------------------------------------------------------------------------
// 64->64 3x3 conv, 8-oc register tile, scalar weights.
// grid (TT, CC/8, nb), block 128 (lane = w).
// mode 0: y = lrelu(conv)*gate[goff+oc]; 1: lrelu; 2: res + lrelu.
// ---------------------------------------------------------------------------
__global__ __launch_bounds__(128)
void k_conv3x3(const float* __restrict__ in, const float* __restrict__ wT,
               const float* __restrict__ bias, const bf16* __restrict__ gate,
               int goff, const float* __restrict__ res, float* __restrict__ y,
               int mode, const float* __restrict__ zrow){
  int b = blockIdx.z, o0 = blockIdx.y*8, h = blockIdx.x;
  int wv = threadIdx.x;
  float acc[8];
  #pragma unroll
  for (int i=0;i<8;++i) acc[i] = bias[o0+i];
  const float* inb = in + (size_t)b*CC*PP;
  for (int ic=0; ic<64; ++ic){
    const float* plane = inb + ic*PP;
    #pragma unroll
    for (int dh=0; dh<3; ++dh){
      int hh = h + dh - 1;
      const float* row = (hh >= 0 && hh < TT) ? plane + hh*TT : zrow;
      float x0 = (wv>=1)  ? row[wv-1] : 0.f;
      float x1 = row[wv];
      float x2 = (wv<=126)? row[wv+1] : 0.f;
      const float* wr = wT + (ic*3+dh)*3*64 + o0;
      #pragma unroll
      for (int i=0;i<8;++i)
        acc[i] += wr[i]*x0 + wr[64+i]*x1 + wr[128+i]*x2;
    }
  }
  int pi = h*TT + wv;
  #pragma unroll
  for (int i=0;i<8;++i){
    float v = acc[i] > 0.f ? acc[i] : 0.1f*acc[i];
    float outv;
    if (mode == 0)      outv = v * b2f(gate[((size_t)b*C3 + goff + o0+i)*PP + pi]);
    else if (mode == 1) outv = v;
    else                outv = v + res[((size_t)b*CC + o0+i)*PP + pi];
    y[((size_t)b*CC + o0+i)*PP + pi] = outv;
  }
}

// ---------------------------------------------------------------------------
// x_cw: H-as-channels conv, 8-ho register tile, scalar weights.
// grid (TT/8, CC, nb), block 128 (lane = w).
// ---------------------------------------------------------------------------
__global__ __launch_bounds__(128)
void k_convcw(const float* __restrict__ x, const float* __restrict__ wcwT,
              const float* __restrict__ bias, const bf16* __restrict__ g,
              float* __restrict__ y){
  int b = blockIdx.z, c = blockIdx.y, ho0 = blockIdx.x*8;
  int wv = threadIdx.x;
  float acc[8];
  #pragma unroll
  for (int i=0;i<8;++i) acc[i] = bias[ho0+i];
  #pragma unroll
  for (int dc=0; dc<3; ++dc){
    int cc = c + dc - 1;
    if (cc < 0 || cc >= CC) continue;
    const float* xp = x + ((size_t)b*CC + cc)*PP;
    for (int hi=0; hi<TT; ++hi){
      const float* row = xp + hi*TT;
      float x0 = (wv>=1)  ? row[wv-1] : 0.f;
      float x1 = row[wv];
      float x2 = (wv<=126)? row[wv+1] : 0.f;
      const float* wr = wcwT + (hi*3+dc)*3*128 + ho0;
      #pragma unroll
      for (int i=0;i<8;++i)
        acc[i] += wr[i]*x0 + wr[128+i]*x1 + wr[256+i]*x2;
    }
  }
  #pragma unroll
  for (int i=0;i<8;++i){
    int pi = (ho0+i)*TT + wv;
    float v = acc[i] > 0.f ? acc[i] : 0.1f*acc[i];
    v *= b2f(g[((size_t)b*C3 + 64 + c)*PP + pi]);
    y[(((size_t)b*CC + c)*TT + ho0+i)*TT + wv] = v;
  }
}

// ---------------------------------------------------------------------------
// x_hc: W-as-channels conv. lane = wo, 16-c register tile; x loads are
// wave-uniform (scalar pipe), weight is the lane-varying vector load.
// grid (TT, CC/16, nb), block 128.
// ---------------------------------------------------------------------------
__global__ __launch_bounds__(128)
void k_convhc(const float* __restrict__ x, const float* __restrict__ whcT,
              const float* __restrict__ bias, const bf16* __restrict__ g,
              float* __restrict__ y, const float* __restrict__ zrow){
  int b = blockIdx.z, c0 = blockIdx.y*16, h = blockIdx.x;
  int wo = threadIdx.x;
  float bias_v = bias[wo];
  float acc[16];
  #pragma unroll
  for (int j=0;j<16;++j) acc[j] = bias_v;
  #pragma unroll
  for (int t9=0; t9<9; ++t9){
    int dh = t9/3, dc = t9%3;
    int hh = h + dh - 1;
    bool hok = (hh >= 0 && hh < TT);
    const float* rp[16];
    #pragma unroll
    for (int j=0;j<16;++j){
      int cc = c0 + j + dc - 1;
      rp[j] = (hok && cc >= 0 && cc < CC)
            ? x + (((size_t)b*CC + cc)*TT + hh)*TT
            : zrow;
    }
    const float* wp = whcT + (size_t)t9*128*128 + wo;
    for (int wi=0; wi<128; ++wi){
      float wt = wp[wi*128];
      #pragma unroll
      for (int j=0;j<16;++j) acc[j] += wt * rp[j][wi];
    }
  }
  int pi = h*TT + wo;
  #pragma unroll
  for (int j=0;j<16;++j){
    int c = c0 + j;
    float v = acc[j] > 0.f ? acc[j] : 0.1f*acc[j];
    v *= b2f(g[((size_t)b*C3 + 128 + c)*PP + pi]);
    y[(((size_t)b*CC + c)*TT + h)*TT + wo] = v;
  }
}

// ---------------------------------------------------------------------------
// folded down-conv (four 1x1s) + residual, 16-o register tile.
// grid (PP/256, CC/16, nb), block 256.
// ---------------------------------------------------------------------------
__global__ void k_down(const float* __restrict__ x, const float* __restrict__ xhw,
                       const float* __restrict__ xcw, const float* __restrict__ xhc,
                       const float* __restrict__ wcT, const float* __restrict__ bias,
                       float* __restrict__ outb){
  int b = blockIdx.z, o0 = blockIdx.y*16;
  int p = blockIdx.x*256 + threadIdx.x;
  float acc[16];
  #pragma unroll
  for (int i=0;i<16;++i) acc[i] = bias[o0+i];
  size_t base = (size_t)b*CC*PP + p;
  for (int k=0;k<64;++k){
    size_t off = base + (size_t)k*PP;
    float xv = x[off], hv = xhw[off], cv = xcw[off], av = xhc[off];
    const float* w0 = wcT + 0*4096 + k*64 + o0;
    const float* w1 = wcT + 1*4096 + k*64 + o0;
    const float* w2 = wcT + 2*4096 + k*64 + o0;
    const float* w3 = wcT + 3*4096 + k*64 + o0;
    #pragma unroll
    for (int i=0;i<16;++i)
      acc[i] += w0[i]*xv + w1[i]*hv + w2[i]*cv + w3[i]*av;
  }
  #pragma unroll
  for (int i=0;i<16;++i){
    acc[i] += x[base + (size_t)(o0+i)*PP];
    outb[((size_t)b*CC + o0+i)*PP + p] = acc[i];
  }
}

// ---------------------------------------------------------------------------
extern "C" void kernel_launch(void* const* d_in, const int* in_sizes, int n_in,
                              void* d_out, int out_size, void* d_ws, size_t ws_size,
                              hipStream_t stream) {
  const float* x      = (const float*)d_in[0];
  const float* w_hwc  = (const float*)d_in[1];
  const float* b_hwc  = (const float*)d_in[2];
  const float* w_dw   = (const float*)d_in[3];
  const float* b_dw   = (const float*)d_in[4];
  const float* w_hw   = (const float*)d_in[5];
  const float* b_hw   = (const float*)d_in[6];
  const float* w_cw   = (const float*)d_in[7];
  const float* b_cw   = (const float*)d_in[8];
  const float* w_hc   = (const float*)d_in[9];
  const float* b_hc   = (const float*)d_in[10];
  const float* w_down = (const float*)d_in[11];
  const float* b_down = (const float*)d_in[12];
  const float* w_l1   = (const float*)d_in[13];
  const float* b_l1   = (const float*)d_in[14];
  const float* w_l2   = (const float*)d_in[15];
  const float* b_l2   = (const float*)d_in[16];
  float* out = (float*)d_out;

  char* ws = (char*)d_ws;
  // ---- meta region (2 MB) ----
  float* wcT  = (float*)(ws + 0);          // 64 KB
  float* whcT = (float*)(ws + 65536);      // 576 KB
  float* wcwT = (float*)(ws + 655360);     // 576 KB
  float* w1T  = (float*)(ws + 1245184);    // 48 KB
  float* whwT = (float*)(ws + 1294336);    // 144 KB
  float* wl1T = (float*)(ws + 1441792);    // 144 KB
  float* wl2T = (float*)(ws + 1589248);    // 144 KB
  float* zrow = (float*)(ws + 1736704);    // 512 B

  k_prep<<<576, 256, 0, stream>>>(w_down, w_hc, w_cw, w_hwc, w_hw, w_l1, w_l2,
                                  wcT, whcT, wcwT, w1T, whwT, wl1T, wl2T, zrow);

  if (ws_size >= 153092096ull) {
    // ---- full-batch path (146 MB) ----
    bf16*  g   = (bf16*) (ws + 2097152);    // 48 MB  -> 52428800
    float* xhw = (float*)(ws + 52428800);   // 32 MB
    float* xcw = (float*)(ws + 85983232);   // 32 MB
    float* xhc = (float*)(ws + 119537664);  // 32 MB  -> 153092096
    float* o1  = (float*)(ws + 2097152);    // aliases g (dead after gating convs)
    float* t   = out;                       // d_out as 1x1 scratch (12.6 MB used)

    for (int b = 0; b < BB; ++b){
      k_1x1<<<dim3(PP/256, 12), 256, 0, stream>>>(x + (size_t)b*CC*PP, w1T, b_hwc, t);
      k_dw <<<dim3(PP/256, C3), 256, 0, stream>>>(t, w_dw, b_dw, g + (size_t)b*C3*PP);
    }
    k_conv3x3<<<dim3(TT, CC/8, BB), 128, 0, stream>>>(x, whwT, b_hw, g, 0, nullptr, xhw, 0, zrow);
    k_convcw <<<dim3(TT/8, CC, BB), 128, 0, stream>>>(x, wcwT, b_cw, g, xcw);
    k_convhc <<<dim3(TT, CC/16, BB), 128, 0, stream>>>(x, whcT, b_hc, g, xhc, zrow);
    k_down   <<<dim3(PP/256, CC/16, BB), 256, 0, stream>>>(x, xhw, xcw, xhc, wcT, b_down, out);
    k_conv3x3<<<dim3(TT, CC/8, BB), 128, 0, stream>>>(out, wl1T, b_l1, nullptr, 0, nullptr, o1, 1, zrow);
    k_conv3x3<<<dim3(TT, CC/8, BB), 128, 0, stream>>>(o1, wl2T, b_l2, nullptr, 0, x, out, 2, zrow);
  } else {
    // ---- per-batch path (~38 MB) ----
    char* P = ws + 2097152;
    float* t_b   = (float*)(P);              // 12.6 MB
    bf16*  g_b   = (bf16*) (P + 12582912);   // 6 MB
    float* xhw_b = (float*)(P + 18874368);   // 4 MB
    float* xcw_b = (float*)(P + 23068672);   // 4 MB
    float* xhc_b = (float*)(P + 27262976);   // 4 MB
    float* o1_b  = (float*)(P + 31457280);   // 4 MB -> 35651584
    for (int b = 0; b < BB; ++b){
      const float* xb = x + (size_t)b*CC*PP;
      float* outb = out + (size_t)b*CC*PP;
      k_1x1<<<dim3(PP/256, 12), 256, 0, stream>>>(xb, w1T, b_hwc, t_b);
      k_dw <<<dim3(PP/256, C3), 256, 0, stream>>>(t_b, w_dw, b_dw, g_b);
      k_conv3x3<<<dim3(TT, CC/8, 1), 128, 0, stream>>>(xb, whwT, b_hw, g_b, 0, nullptr, xhw_b, 0, zrow);
      k_convcw <<<dim3(TT/8, CC, 1), 128, 0, stream>>>(xb, wcwT, b_cw, g_b, xcw_b);
      k_convhc <<<dim3(TT, CC/16, 1), 128, 0, stream>>>(xb, whcT, b_hc, g_b, xhc_b, zrow);
      k_down   <<<dim3(PP/256, CC/16, 1), 256, 0, stream>>>(xb, xhw_b, xcw_b, xhc_b, wcT, b_down, outb);
      k_conv3x3<<<dim3(TT, CC/8, 1), 128, 0, stream>>>(outb, wl1T, b_l1, nullptr, 0, nullptr, o1_b, 1, zrow);
      k_conv3x3<<<dim3(TT, CC/8, 1), 128, 0, stream>>>(o1_b, wl2T, b_l2, nullptr, 0, xb, outb, 2, zrow);
    }
  }
}

// Round 5
// 1409.504 us; speedup vs baseline: 3.2990x; 1.9001x over previous
//
#include <hip/hip_runtime.h>
#include <hip/hip_bf16.h>

#define BB 8
#define CC 64
#define TT 128
#define PP (TT*TT)
#define C3 192

typedef __hip_bfloat16 bf16;
__device__ __forceinline__ float b2f(bf16 v){ return __bfloat162float(v); }
__device__ __forceinline__ bf16 f2b(float v){ return __float2bfloat16(v); }

// ---------------------------------------------------------------------------
// prep: weight transposes (wave-uniform scalar loads), folded down-conv
// weights, zero row for OOB row pointers.
// ---------------------------------------------------------------------------
__global__ void k_prep(const float* __restrict__ w_down, const float* __restrict__ w_hc,
                       const float* __restrict__ w_cw,  const float* __restrict__ w_hwc,
                       const float* __restrict__ w_hw,  const float* __restrict__ w_l1,
                       const float* __restrict__ w_l2,
                       float* __restrict__ wcT,  float* __restrict__ whcT,
                       float* __restrict__ wcwT, float* __restrict__ w1T,
                       float* __restrict__ whwT, float* __restrict__ wl1T,
                       float* __restrict__ wl2T, float* __restrict__ zrow){
  int i = blockIdx.x*256 + threadIdx.x;
  if (i < 128*128*9){
    int a  = i / 1152;          // wo (hc) / ho (cw)
    int r  = i % 1152;
    int m  = r / 9;             // wi (hc) / hi (cw)
    int t  = r % 9;
    // w_hc[wo][wi][dh][dc] -> whcT[((dh*3+dc)*128+wi)*128 + wo]
    whcT[(t*128 + m)*128 + a] = w_hc[i];
    // w_cw[ho][hi][dc][dw] -> wcwT[((hi*3+dc)*3+dw)*128 + ho]
    wcwT[(m*9 + t)*128 + a] = w_cw[i];
  }
  if (i < 12288){               // w_hwc[oc192][ic64] -> w1T[ic*192+oc]
    int oc = i / 64, ic = i % 64;
    w1T[ic*192 + oc] = w_hwc[i];
  }
  if (i < 36864){               // w[oc64][ic64][3][3] -> wT[(ic*9+t)*64+oc]
    int oc = i / 576; int r = i % 576; int ic = r / 9; int t = r % 9;
    whwT[(ic*9+t)*64 + oc] = w_hw[i];
    wl1T[(ic*9+t)*64 + oc] = w_l1[i];
    wl2T[(ic*9+t)*64 + oc] = w_l2[i];
  }
  if (i < 4096){                // folded down weights, [r][k][o] layout
    int o = i >> 6, k = i & 63;
    const float* wd = w_down + o*512 + k*8;
    wcT[0*4096 + k*64 + o] = wd[0] + wd[7];  // X
    wcT[1*4096 + k*64 + o] = wd[1] + wd[6];  // HW
    wcT[2*4096 + k*64 + o] = wd[2] + wd[5];  // CW
    wcT[3*4096 + k*64 + o] = wd[3] + wd[4];  // HC
  }
  if (i < 128) zrow[i] = 0.f;
}

// ---------------------------------------------------------------------------
// x transpose for convhc: xT[b][hr=h+1 (130)][wi (128)][72] where
// row[cs] = x[b][cs-1][h][wi] for cs in 1..64, 0 elsewhere (c-pad + zero
// rows hr=0,129). LDS-tiled, fully coalesced both sides.
// grid (130, nb), block 256.
// ---------------------------------------------------------------------------
__global__ void k_xT(const float* __restrict__ x, float* __restrict__ xT){
  int hr = blockIdx.x, b = blockIdx.y;
  float* dst = xT + ((size_t)b*130 + hr)*128*72;
  if (hr == 0 || hr == 129){
    for (int idx = threadIdx.x; idx < 128*72; idx += 256) dst[idx] = 0.f;
    return;
  }
  int h = hr - 1;
  __shared__ float xs[64][129];
  const float* src = x + (size_t)b*CC*PP + h*TT;
  #pragma unroll 4
  for (int it = 0; it < 32; ++it){
    int c  = it*2 + (threadIdx.x >> 7);
    int wi = threadIdx.x & 127;
    xs[c][wi] = src[(size_t)c*PP + wi];
  }
  __syncthreads();
  for (int idx = threadIdx.x; idx < 128*72; idx += 256){
    int wi = idx / 72, cs = idx % 72;
    float v = (cs >= 1 && cs < 65) ? xs[cs-1][wi] : 0.f;
    dst[idx] = v;
  }
}

// ---------------------------------------------------------------------------
// 1x1 expand, 16-oc register tile: t[ch,p] for one batch.
// ---------------------------------------------------------------------------
__global__ void k_1x1(const float* __restrict__ xb, const float* __restrict__ w1T,
                      const float* __restrict__ b_hwc, float* __restrict__ t){
  int p  = blockIdx.x*256 + threadIdx.x;
  int c0 = blockIdx.y*16;
  float acc[16];
  #pragma unroll
  for (int i=0;i<16;++i) acc[i] = b_hwc[c0+i];
  const float* xp = xb + p;
  for (int ic=0; ic<64; ++ic){
    float xv = xp[ic*PP];
    const float* wr = w1T + ic*192 + c0;
    #pragma unroll
    for (int i=0;i<16;++i) acc[i] += wr[i]*xv;
  }
  #pragma unroll
  for (int i=0;i<16;++i) t[(c0+i)*PP + p] = acc[i];
}

// ---------------------------------------------------------------------------
// depthwise 3x3 on t -> bf16 gates for one batch.
// ---------------------------------------------------------------------------
__global__ void k_dw(const float* __restrict__ t, const float* __restrict__ w_dw,
                     const float* __restrict__ b_dw, bf16* __restrict__ gb){
  int ch = blockIdx.y;
  int p  = blockIdx.x*256 + threadIdx.x;
  int h = p >> 7, w = p & 127;
  const float* tp = t + ch*PP;
  const float* wd = w_dw + ch*9;
  float acc = b_dw[ch];
  #pragma unroll
  for (int dh=0; dh<3; ++dh){
    int hh = h + dh - 1;
    if (hh < 0 || hh >= TT) continue;
    const float* row = tp + hh*TT;
    float x0 = (w>=1)  ? row[w-1] : 0.f;
    float x1 = row[w];
    float x2 = (w<=126)? row[w+1] : 0.f;
    acc += wd[dh*3+0]*x0 + wd[dh*3+1]*x1 + wd[dh*3+2]*x2;
  }
  gb[ch*PP + p] = f2b(acc);
}

// ---------------------------------------------------------------------------
// 64->64 3x3 conv, 8-oc register tile, scalar weights.
// grid (TT, CC/8, nb), block 128 (lane = w).
// ---------------------------------------------------------------------------
__global__ __launch_bounds__(128)
void k_conv3x3(const float* __restrict__ in, const float* __restrict__ wT,
               const float* __restrict__ bias, const bf16* __restrict__ gate,
               int goff, const float* __restrict__ res, float* __restrict__ y,
               int mode, const float* __restrict__ zrow){
  int b = blockIdx.z, o0 = blockIdx.y*8, h = blockIdx.x;
  int wv = threadIdx.x;
  float acc[8];
  #pragma unroll
  for (int i=0;i<8;++i) acc[i] = bias[o0+i];
  const float* inb = in + (size_t)b*CC*PP;
  for (int ic=0; ic<64; ++ic){
    const float* plane = inb + ic*PP;
    #pragma unroll
    for (int dh=0; dh<3; ++dh){
      int hh = h + dh - 1;
      const float* row = (hh >= 0 && hh < TT) ? plane + hh*TT : zrow;
      float x0 = (wv>=1)  ? row[wv-1] : 0.f;
      float x1 = row[wv];
      float x2 = (wv<=126)? row[wv+1] : 0.f;
      const float* wr = wT + (ic*3+dh)*3*64 + o0;
      #pragma unroll
      for (int i=0;i<8;++i)
        acc[i] += wr[i]*x0 + wr[64+i]*x1 + wr[128+i]*x2;
    }
  }
  int pi = h*TT + wv;
  #pragma unroll
  for (int i=0;i<8;++i){
    float v = acc[i] > 0.f ? acc[i] : 0.1f*acc[i];
    float outv;
    if (mode == 0)      outv = v * b2f(gate[((size_t)b*C3 + goff + o0+i)*PP + pi]);
    else if (mode == 1) outv = v;
    else                outv = v + res[((size_t)b*CC + o0+i)*PP + pi];
    y[((size_t)b*CC + o0+i)*PP + pi] = outv;
  }
}

// ---------------------------------------------------------------------------
// x_cw: H-as-channels conv, 8-ho register tile, scalar weights.
// grid (TT/8, CC, nb), block 128 (lane = w).
// ---------------------------------------------------------------------------
__global__ __launch_bounds__(128)
void k_convcw(const float* __restrict__ x, const float* __restrict__ wcwT,
              const float* __restrict__ bias, const bf16* __restrict__ g,
              float* __restrict__ y){
  int b = blockIdx.z, c = blockIdx.y, ho0 = blockIdx.x*8;
  int wv = threadIdx.x;
  float acc[8];
  #pragma unroll
  for (int i=0;i<8;++i) acc[i] = bias[ho0+i];
  #pragma unroll
  for (int dc=0; dc<3; ++dc){
    int cc = c + dc - 1;
    if (cc < 0 || cc >= CC) continue;
    const float* xp = x + ((size_t)b*CC + cc)*PP;
    for (int hi=0; hi<TT; ++hi){
      const float* row = xp + hi*TT;
      float x0 = (wv>=1)  ? row[wv-1] : 0.f;
      float x1 = row[wv];
      float x2 = (wv<=126)? row[wv+1] : 0.f;
      const float* wr = wcwT + (hi*3+dc)*3*128 + ho0;
      #pragma unroll
      for (int i=0;i<8;++i)
        acc[i] += wr[i]*x0 + wr[128+i]*x1 + wr[256+i]*x2;
    }
  }
  #pragma unroll
  for (int i=0;i<8;++i){
    int pi = (ho0+i)*TT + wv;
    float v = acc[i] > 0.f ? acc[i] : 0.1f*acc[i];
    v *= b2f(g[((size_t)b*C3 + 64 + c)*PP + pi]);
    y[(((size_t)b*CC + c)*TT + ho0+i)*TT + wv] = v;
  }
}

// ---------------------------------------------------------------------------
// x_hc rewrite: lane = c, 16-wo register tile per wave.
// Per k-step (t9,wi): 1 coalesced vector load of xT + 2 s_load_dwordx8 of
// weights (wave-uniform) + 16 v_fma (SGPR weight operand). VALU-bound.
// grid (TT, 2, nb), block 256 (4 waves; wave w covers wo0 = y*64 + w*16).
// ---------------------------------------------------------------------------
__global__ __launch_bounds__(256)
void k_convhc(const float* __restrict__ xT, const float* __restrict__ whcT,
              const float* __restrict__ bias, const bf16* __restrict__ g,
              float* __restrict__ y){
  int b = blockIdx.z, h = blockIdx.x;
  int lane = threadIdx.x & 63;                                   // = c
  int wvid = __builtin_amdgcn_readfirstlane(threadIdx.x >> 6);   // wave id, uniform
  int wo0 = blockIdx.y*64 + wvid*16;
  float acc[16];
  #pragma unroll
  for (int j=0;j<16;++j) acc[j] = bias[wo0+j];
  #pragma unroll
  for (int t9=0; t9<9; ++t9){
    int dh = t9/3, dc = t9%3;
    const float* xrow = xT + (((size_t)b*130 + h + dh)*128)*72 + dc + lane;
    const float* wrow = whcT + t9*16384 + wo0;
    #pragma unroll 2
    for (int wi=0; wi<128; ++wi){
      float xv = xrow[(size_t)wi*72];
      #pragma unroll
      for (int j=0;j<16;++j) acc[j] += wrow[wi*128 + j] * xv;
    }
  }
  int c = lane;
  size_t gbase = ((size_t)b*C3 + 128 + c)*PP + h*TT + wo0;
  size_t ybase = (((size_t)b*CC + c)*TT + h)*TT + wo0;
  float ov[16];
  #pragma unroll
  for (int j=0;j<16;++j){
    float v = acc[j] > 0.f ? acc[j] : 0.1f*acc[j];
    ov[j] = v * b2f(g[gbase + j]);
  }
  #pragma unroll
  for (int j=0;j<4;++j)
    *(float4*)(y + ybase + j*4) = make_float4(ov[j*4], ov[j*4+1], ov[j*4+2], ov[j*4+3]);
}

// ---------------------------------------------------------------------------
// folded down-conv (four 1x1s) + residual, 16-o register tile.
// ---------------------------------------------------------------------------
__global__ void k_down(const float* __restrict__ x, const float* __restrict__ xhw,
                       const float* __restrict__ xcw, const float* __restrict__ xhc,
                       const float* __restrict__ wcT, const float* __restrict__ bias,
                       float* __restrict__ outb){
  int b = blockIdx.z, o0 = blockIdx.y*16;
  int p = blockIdx.x*256 + threadIdx.x;
  float acc[16];
  #pragma unroll
  for (int i=0;i<16;++i) acc[i] = bias[o0+i];
  size_t base = (size_t)b*CC*PP + p;
  for (int k=0;k<64;++k){
    size_t off = base + (size_t)k*PP;
    float xv = x[off], hv = xhw[off], cv = xcw[off], av = xhc[off];
    const float* w0 = wcT + 0*4096 + k*64 + o0;
    const float* w1 = wcT + 1*4096 + k*64 + o0;
    const float* w2 = wcT + 2*4096 + k*64 + o0;
    const float* w3 = wcT + 3*4096 + k*64 + o0;
    #pragma unroll
    for (int i=0;i<16;++i)
      acc[i] += w0[i]*xv + w1[i]*hv + w2[i]*cv + w3[i]*av;
  }
  #pragma unroll
  for (int i=0;i<16;++i){
    acc[i] += x[base + (size_t)(o0+i)*PP];
    outb[((size_t)b*CC + o0+i)*PP + p] = acc[i];
  }
}

// ---------------------------------------------------------------------------
extern "C" void kernel_launch(void* const* d_in, const int* in_sizes, int n_in,
                              void* d_out, int out_size, void* d_ws, size_t ws_size,
                              hipStream_t stream) {
  const float* x      = (const float*)d_in[0];
  const float* w_hwc  = (const float*)d_in[1];
  const float* b_hwc  = (const float*)d_in[2];
  const float* w_dw   = (const float*)d_in[3];
  const float* b_dw   = (const float*)d_in[4];
  const float* w_hw   = (const float*)d_in[5];
  const float* b_hw   = (const float*)d_in[6];
  const float* w_cw   = (const float*)d_in[7];
  const float* b_cw   = (const float*)d_in[8];
  const float* w_hc   = (const float*)d_in[9];
  const float* b_hc   = (const float*)d_in[10];
  const float* w_down = (const float*)d_in[11];
  const float* b_down = (const float*)d_in[12];
  const float* w_l1   = (const float*)d_in[13];
  const float* b_l1   = (const float*)d_in[14];
  const float* w_l2   = (const float*)d_in[15];
  const float* b_l2   = (const float*)d_in[16];
  float* out = (float*)d_out;

  char* ws = (char*)d_ws;
  // ---- meta region (2 MB) ----
  float* wcT  = (float*)(ws + 0);          // 64 KB
  float* whcT = (float*)(ws + 65536);      // 576 KB
  float* wcwT = (float*)(ws + 655360);     // 576 KB
  float* w1T  = (float*)(ws + 1245184);    // 48 KB
  float* whwT = (float*)(ws + 1294336);    // 144 KB
  float* wl1T = (float*)(ws + 1441792);    // 144 KB
  float* wl2T = (float*)(ws + 1589248);    // 144 KB
  float* zrow = (float*)(ws + 1736704);    // 512 B

  k_prep<<<576, 256, 0, stream>>>(w_down, w_hc, w_cw, w_hwc, w_hw, w_l1, w_l2,
                                  wcT, whcT, wcwT, w1T, whwT, wl1T, wl2T, zrow);

  if (ws_size >= 191430656ull) {
    // ---- full-batch path (~183 MB) ----
    bf16*  g   = (bf16*) (ws + 2097152);    // 48 MB  -> 52428800
    float* xhw = (float*)(ws + 52428800);   // 32 MB
    float* xcw = (float*)(ws + 85983232);   // 32 MB
    float* xhc = (float*)(ws + 119537664);  // 32 MB  -> 153092096
    float* xT  = (float*)(ws + 153092096);  // 36.6 MB -> 191430656
    float* o1  = (float*)(ws + 2097152);    // aliases g (dead after gating convs)
    float* t   = out;                       // d_out as 1x1 scratch

    k_xT<<<dim3(130, BB), 256, 0, stream>>>(x, xT);
    for (int b = 0; b < BB; ++b){
      k_1x1<<<dim3(PP/256, 12), 256, 0, stream>>>(x + (size_t)b*CC*PP, w1T, b_hwc, t);
      k_dw <<<dim3(PP/256, C3), 256, 0, stream>>>(t, w_dw, b_dw, g + (size_t)b*C3*PP);
    }
    k_conv3x3<<<dim3(TT, CC/8, BB), 128, 0, stream>>>(x, whwT, b_hw, g, 0, nullptr, xhw, 0, zrow);
    k_convcw <<<dim3(TT/8, CC, BB), 128, 0, stream>>>(x, wcwT, b_cw, g, xcw);
    k_convhc <<<dim3(TT, 2, BB), 256, 0, stream>>>(xT, whcT, b_hc, g, xhc);
    k_down   <<<dim3(PP/256, CC/16, BB), 256, 0, stream>>>(x, xhw, xcw, xhc, wcT, b_down, out);
    k_conv3x3<<<dim3(TT, CC/8, BB), 128, 0, stream>>>(out, wl1T, b_l1, nullptr, 0, nullptr, o1, 1, zrow);
    k_conv3x3<<<dim3(TT, CC/8, BB), 128, 0, stream>>>(o1, wl2T, b_l2, nullptr, 0, x, out, 2, zrow);
  } else {
    // ---- per-batch path (~42 MB) ----
    char* P = ws + 2097152;
    float* t_b   = (float*)(P);              // 12.6 MB
    bf16*  g_b   = (bf16*) (P + 12582912);   // 6 MB
    float* xhw_b = (float*)(P + 18874368);   // 4 MB
    float* xcw_b = (float*)(P + 23068672);   // 4 MB
    float* xhc_b = (float*)(P + 27262976);   // 4 MB
    float* o1_b  = (float*)(P + 31457280);   // 4 MB
    float* xT_b  = (float*)(P + 35651584);   // 4.6 MB -> 40443904
    for (int b = 0; b < BB; ++b){
      const float* xb = x + (size_t)b*CC*PP;
      float* outb = out + (size_t)b*CC*PP;
      k_xT<<<dim3(130, 1), 256, 0, stream>>>(xb, xT_b);
      k_1x1<<<dim3(PP/256, 12), 256, 0, stream>>>(xb, w1T, b_hwc, t_b);
      k_dw <<<dim3(PP/256, C3), 256, 0, stream>>>(t_b, w_dw, b_dw, g_b);
      k_conv3x3<<<dim3(TT, CC/8, 1), 128, 0, stream>>>(xb, whwT, b_hw, g_b, 0, nullptr, xhw_b, 0, zrow);
      k_convcw <<<dim3(TT/8, CC, 1), 128, 0, stream>>>(xb, wcwT, b_cw, g_b, xcw_b);
      k_convhc <<<dim3(TT, 2, 1), 256, 0, stream>>>(xT_b, whcT, b_hc, g_b, xhc_b);
      k_down   <<<dim3(PP/256, CC/16, 1), 256, 0, stream>>>(xb, xhw_b, xcw_b, xhc_b, wcT, b_down, outb);
      k_conv3x3<<<dim3(TT, CC/8, 1), 128, 0, stream>>>(outb, wl1T, b_l1, nullptr, 0, nullptr, o1_b, 1, zrow);
      k_conv3x3<<<dim3(TT, CC/8, 1), 128, 0, stream>>>(o1_b, wl2T, b_l2, nullptr, 0, xb, outb, 2, zrow);
    }
  }
}

// Round 6
// 592.588 us; speedup vs baseline: 7.8468x; 2.3786x over previous
//
#include <hip/hip_runtime.h>
#include <hip/hip_bf16.h>

#define BB 8
#define CC 64
#define TT 128
#define PP (TT*TT)
#define C3 192

typedef __hip_bfloat16 bf16;
typedef __attribute__((ext_vector_type(8))) short short8;
typedef __attribute__((ext_vector_type(4))) float floatx4;

__device__ __forceinline__ float b2f(bf16 v){ return __bfloat162float(v); }
__device__ __forceinline__ bf16 f2b(float v){ return __float2bfloat16(v); }
__device__ __forceinline__ short8 lds8(const bf16* p){ return *(const short8*)(const void*)p; }

// ---------------------------------------------------------------------------
// k_wpk: weight prepack into MFMA A-frag lane order + folded down weights.
// A[m][k] frag: m = mm*16 + (lane&15), k = kk*32 + (lane>>4)*8 + j.
// ---------------------------------------------------------------------------
__global__ void k_wpk(const float* __restrict__ w_down, const float* __restrict__ w_hc,
                      const float* __restrict__ w_cw,  const float* __restrict__ w_hwc,
                      const float* __restrict__ w_hw,  const float* __restrict__ w_l1,
                      const float* __restrict__ w_l2,
                      float* __restrict__ wcT, bf16* __restrict__ wpk1,
                      bf16* __restrict__ wpkhw, bf16* __restrict__ wpkl1,
                      bf16* __restrict__ wpkl2, bf16* __restrict__ wpkcw,
                      bf16* __restrict__ wpkhc){
  int i = blockIdx.x*256 + threadIdx.x;
  if (i < 147456){   // cw: t=dc*3+dw ; hc: t=dh*3+dc ; M=128,K=128
    int j = i & 7, lane = (i>>3) & 63, mm = (i>>9) & 7, kk = (i>>12) & 3, t = i >> 14;
    int m = mm*16 + (lane & 15);
    int k = kk*32 + (lane>>4)*8 + j;
    wpkcw[i] = f2b(w_cw[m*1152 + k*9 + t]);
    wpkhc[i] = f2b(w_hc[m*1152 + k*9 + t]);
  }
  if (i < 36864){    // hw/l1/l2: M=64,K=64, t=dh*3+dw
    int j = i & 7, lane = (i>>3) & 63, mm = (i>>9) & 3, kk = (i>>11) & 1, t = i >> 12;
    int oc = mm*16 + (lane & 15);
    int ic = kk*32 + (lane>>4)*8 + j;
    int s = oc*576 + ic*9 + t;
    wpkhw[i] = f2b(w_hw[s]);
    wpkl1[i] = f2b(w_l1[s]);
    wpkl2[i] = f2b(w_l2[s]);
  }
  if (i < 12288){    // 1x1: M=192 (mm 0..11), K=64
    int j = i & 7, lane = (i>>3) & 63, rest = i >> 9;
    int mm = rest % 12, kk = rest / 12;
    int oc = mm*16 + (lane & 15);
    int ic = kk*32 + (lane>>4)*8 + j;
    wpk1[((kk*12+mm)*64 + lane)*8 + j] = f2b(w_hwc[oc*64 + ic]);
  }
  if (i < 4096){     // folded down-conv weights [r][k][o]
    int o = i >> 6, k = i & 63;
    const float* wd = w_down + o*512 + k*8;
    wcT[0*4096 + k*64 + o] = wd[0] + wd[7];  // X
    wcT[1*4096 + k*64 + o] = wd[1] + wd[6];  // HW
    wcT[2*4096 + k*64 + o] = wd[2] + wd[5];  // CW
    wcT[3*4096 + k*64 + o] = wd[3] + wd[4];  // HC
  }
}

// ---------------------------------------------------------------------------
// packs: xh = NHWC bf16 [b][h][w][c]; xW = [b][c][w][h] bf16; xb16 = NCHW bf16
// ---------------------------------------------------------------------------
__global__ void k_xh(const float* __restrict__ x, bf16* __restrict__ xh){
  int h = blockIdx.x, b = blockIdx.y;
  __shared__ float xs[64][129];
  for (int idx = threadIdx.x; idx < 8192; idx += 256){
    int c = idx >> 7, w = idx & 127;
    xs[c][w] = x[((size_t)b*CC + c)*PP + h*TT + w];
  }
  __syncthreads();
  for (int idx = threadIdx.x; idx < 8192; idx += 256){
    int w = idx >> 6, c = idx & 63;
    xh[(((size_t)b*TT + h)*TT + w)*64 + c] = f2b(xs[c][w]);
  }
}

__global__ void k_xw(const float* __restrict__ x, bf16* __restrict__ xW){
  int c = blockIdx.x, b = blockIdx.y;
  __shared__ float xs2[32][129];
  const float* src = x + ((size_t)b*CC + c)*PP;
  bf16* dst = xW + ((size_t)b*CC + c)*PP;
  for (int s = 0; s < 4; ++s){
    for (int idx = threadIdx.x; idx < 4096; idx += 256){
      int hl = idx >> 7, w = idx & 127;
      xs2[hl][w] = src[(s*32 + hl)*TT + w];
    }
    __syncthreads();
    for (int idx = threadIdx.x; idx < 4096; idx += 256){
      int w = idx >> 5, hl = idx & 31;
      dst[w*TT + s*32 + hl] = f2b(xs2[hl][w]);
    }
    __syncthreads();
  }
}

__global__ void k_xb(const float* __restrict__ x, bf16* __restrict__ xb, int n4){
  int i = blockIdx.x*256 + threadIdx.x;
  if (i >= n4) return;
  const float4 v = *(const float4*)(x + (size_t)i*4);
  bf16 o[4] = { f2b(v.x), f2b(v.y), f2b(v.z), f2b(v.w) };
  *(uint2*)(xb + (size_t)i*4) = *(uint2*)o;
}

// ---------------------------------------------------------------------------
// k_1x1m: MFMA 1x1 expand. C[oc 192][w 128] per (b,h). t NHWC bf16 [b][p][192].
// grid (128, nb), block 256.
// ---------------------------------------------------------------------------
__global__ __launch_bounds__(256)
void k_1x1m(const bf16* __restrict__ xh, const bf16* __restrict__ wpk1,
            const float* __restrict__ bias, bf16* __restrict__ t){
  int h = blockIdx.x, b = blockIdx.y;
  int tid = threadIdx.x, lane = tid & 63, wv = tid >> 6;
  int nlo = lane & 15, quad = lane >> 4;
  __shared__ bf16 xs[128][64];
  for (int idx = tid; idx < 1024; idx += 256){
    int w = idx >> 3, c8 = (idx & 7)*8;
    *(uint4*)(&xs[w][c8]) = *(const uint4*)(xh + (((size_t)b*TT + h)*TT + w)*64 + c8);
  }
  __syncthreads();
  int n0 = wv*32;
  floatx4 acc[12][2] = {};
  #pragma unroll
  for (int kk = 0; kk < 2; ++kk){
    short8 b0 = lds8(&xs[n0 + nlo][kk*32 + quad*8]);
    short8 b1 = lds8(&xs[n0 + 16 + nlo][kk*32 + quad*8]);
    #pragma unroll
    for (int mm = 0; mm < 12; ++mm){
      short8 a = *(const short8*)(const void*)(wpk1 + ((kk*12+mm)*64 + lane)*8);
      acc[mm][0] = __builtin_amdgcn_mfma_f32_16x16x32_bf16(a, b0, acc[mm][0], 0,0,0);
      acc[mm][1] = __builtin_amdgcn_mfma_f32_16x16x32_bf16(a, b1, acc[mm][1], 0,0,0);
    }
  }
  #pragma unroll
  for (int mm = 0; mm < 12; ++mm){
    int oc0 = mm*16 + quad*4;
    float4 bs = *(const float4*)(bias + oc0);
    #pragma unroll
    for (int nn = 0; nn < 2; ++nn){
      int w = n0 + nn*16 + nlo;
      bf16 o4[4] = { f2b(acc[mm][nn][0] + bs.x), f2b(acc[mm][nn][1] + bs.y),
                     f2b(acc[mm][nn][2] + bs.z), f2b(acc[mm][nn][3] + bs.w) };
      *(uint2*)(t + ((size_t)b*PP + h*TT + w)*C3 + oc0) = *(uint2*)o4;
    }
  }
}

// ---------------------------------------------------------------------------
// k_dwv: depthwise 3x3 on t (NHWC bf16) -> g (NCHW bf16).
// grid (64, 24, nb), block 256: thread = one pixel x 8 channels.
// ---------------------------------------------------------------------------
__global__ void k_dwv(const bf16* __restrict__ t, const float* __restrict__ w_dw,
                      const float* __restrict__ b_dw, bf16* __restrict__ g){
  int p = blockIdx.x*256 + threadIdx.x;
  int ch0 = blockIdx.y*8, b = blockIdx.z;
  int h = p >> 7, w = p & 127;
  float acc[8];
  #pragma unroll
  for (int i=0;i<8;++i) acc[i] = b_dw[ch0+i];
  #pragma unroll
  for (int dh = 0; dh < 3; ++dh){
    int hh = h + dh - 1;
    if (hh < 0 || hh >= TT) continue;
    #pragma unroll
    for (int dw = 0; dw < 3; ++dw){
      int ww = w + dw - 1;
      if (ww < 0 || ww >= TT) continue;
      bf16 v[8];
      *(uint4*)v = *(const uint4*)(t + ((size_t)b*PP + hh*TT + ww)*C3 + ch0);
      #pragma unroll
      for (int i=0;i<8;++i) acc[i] += w_dw[(ch0+i)*9 + dh*3 + dw] * b2f(v[i]);
    }
  }
  #pragma unroll
  for (int i=0;i<8;++i) g[((size_t)b*C3 + ch0+i)*PP + p] = f2b(acc[i]);
}

// ---------------------------------------------------------------------------
// k_c3x3m: MFMA 64->64 3x3 conv over NHWC bf16 input. C[oc 64][w 128] per (b,h).
// mode 0: yb(bf16 NCHW) = lrelu(conv)*g[goff+oc]
// mode 1: yb(bf16 NHWC) = lrelu(conv)
// mode 2: yf(fp32 NCHW) = lrelu(conv) + resx
// grid (128, nb), block 256.
// ---------------------------------------------------------------------------
__global__ __launch_bounds__(256)
void k_c3x3m(const bf16* __restrict__ in, const bf16* __restrict__ wpk,
             const float* __restrict__ bias, const bf16* __restrict__ g, int goff,
             const float* __restrict__ resx, bf16* __restrict__ yb,
             float* __restrict__ yf, int mode){
  int h = blockIdx.x, b = blockIdx.y;
  int tid = threadIdx.x, lane = tid & 63, wv = tid >> 6;
  int nlo = lane & 15, quad = lane >> 4;
  __shared__ bf16 xs[3][130][64];
  for (int idx = tid; idx < 3120; idx += 256){
    int dh = idx / 1040, r = idx % 1040, wi = r >> 3, c8 = (r & 7)*8;
    int gh = h + dh - 1, gw = wi - 1;
    uint4 v = make_uint4(0,0,0,0);
    if (gh >= 0 && gh < TT && gw >= 0 && gw < TT)
      v = *(const uint4*)(in + (((size_t)b*TT + gh)*TT + gw)*64 + c8);
    *(uint4*)(&xs[dh][wi][c8]) = v;
  }
  __syncthreads();
  int n0 = wv*32;
  floatx4 acc[4][2] = {};
  #pragma unroll
  for (int t = 0; t < 9; ++t){
    int dh = t/3, dw = t%3;
    #pragma unroll
    for (int kk = 0; kk < 2; ++kk){
      short8 b0 = lds8(&xs[dh][n0 + nlo + dw][kk*32 + quad*8]);
      short8 b1 = lds8(&xs[dh][n0 + 16 + nlo + dw][kk*32 + quad*8]);
      #pragma unroll
      for (int mm = 0; mm < 4; ++mm){
        short8 a = *(const short8*)(const void*)(wpk + (((t*2+kk)*4+mm)*64 + lane)*8);
        acc[mm][0] = __builtin_amdgcn_mfma_f32_16x16x32_bf16(a, b0, acc[mm][0], 0,0,0);
        acc[mm][1] = __builtin_amdgcn_mfma_f32_16x16x32_bf16(a, b1, acc[mm][1], 0,0,0);
      }
    }
  }
  #pragma unroll
  for (int mm = 0; mm < 4; ++mm){
    int oc0 = mm*16 + quad*4;
    float4 bs = *(const float4*)(bias + oc0);
    float bsa[4] = { bs.x, bs.y, bs.z, bs.w };
    #pragma unroll
    for (int nn = 0; nn < 2; ++nn){
      int w = n0 + nn*16 + nlo;
      int pi = h*TT + w;
      if (mode == 1){
        bf16 o4[4];
        #pragma unroll
        for (int r = 0; r < 4; ++r){
          float v = acc[mm][nn][r] + bsa[r];
          o4[r] = f2b(v > 0.f ? v : 0.1f*v);
        }
        *(uint2*)(yb + (((size_t)b*TT + h)*TT + w)*64 + oc0) = *(uint2*)o4;
      } else {
        #pragma unroll
        for (int r = 0; r < 4; ++r){
          int oc = oc0 + r;
          float v = acc[mm][nn][r] + bsa[r];
          v = v > 0.f ? v : 0.1f*v;
          if (mode == 0){
            v *= b2f(g[((size_t)b*C3 + goff + oc)*PP + pi]);
            yb[((size_t)b*CC + oc)*PP + pi] = f2b(v);
          } else {
            yf[((size_t)b*CC + oc)*PP + pi] = v + resx[((size_t)b*CC + oc)*PP + pi];
          }
        }
      }
    }
  }
}

// ---------------------------------------------------------------------------
// k_cwm: x_cw conv via MFMA. C[ho 128][w 64] per (half, c, b); K = hi*9taps.
// B from xW[b][c][w][h] (h contiguous). out xcw bf16 NCHW gated.
// grid (2, 64, nb), block 256.
// ---------------------------------------------------------------------------
__global__ __launch_bounds__(256)
void k_cwm(const bf16* __restrict__ xW, const bf16* __restrict__ wpkcw,
           const float* __restrict__ bias, const bf16* __restrict__ g,
           bf16* __restrict__ xcw){
  int w0b = blockIdx.x*64, c = blockIdx.y, b = blockIdx.z;
  int tid = threadIdx.x, lane = tid & 63, wv = tid >> 6;
  int nlo = lane & 15, quad = lane >> 4;
  __shared__ bf16 xs[66][128];
  int nloc = wv*16 + nlo;          // w offset within the 64-wide tile
  floatx4 acc[8] = {};
  for (int dc = 0; dc < 3; ++dc){
    int cc = c + dc - 1;
    if (cc < 0 || cc >= CC) continue;         // block-uniform
    __syncthreads();
    for (int idx = tid; idx < 1056; idx += 256){
      int s = idx >> 4, h8 = (idx & 15)*8;
      int gw = w0b - 1 + s;
      uint4 v = make_uint4(0,0,0,0);
      if (gw >= 0 && gw < TT)
        v = *(const uint4*)(xW + (((size_t)b*CC + cc)*TT + gw)*TT + h8);
      *(uint4*)(&xs[s][h8]) = v;
    }
    __syncthreads();
    #pragma unroll
    for (int dw = 0; dw < 3; ++dw){
      int t = dc*3 + dw;
      #pragma unroll
      for (int kk = 0; kk < 4; ++kk){
        short8 bfr = lds8(&xs[nloc + dw][kk*32 + quad*8]);
        #pragma unroll
        for (int mm = 0; mm < 8; ++mm){
          short8 a = *(const short8*)(const void*)(wpkcw + (((t*4+kk)*8+mm)*64 + lane)*8);
          acc[mm] = __builtin_amdgcn_mfma_f32_16x16x32_bf16(a, bfr, acc[mm], 0,0,0);
        }
      }
    }
  }
  int w = w0b + nloc;
  #pragma unroll
  for (int mm = 0; mm < 8; ++mm){
    int ho0 = mm*16 + quad*4;
    float4 bs = *(const float4*)(bias + ho0);
    float bsa[4] = { bs.x, bs.y, bs.z, bs.w };
    #pragma unroll
    for (int r = 0; r < 4; ++r){
      int ho = ho0 + r;
      float v = acc[mm][r] + bsa[r];
      v = v > 0.f ? v : 0.1f*v;
      v *= b2f(g[((size_t)b*C3 + 64 + c)*PP + ho*TT + w]);
      xcw[((size_t)b*CC + c)*PP + ho*TT + w] = f2b(v);
    }
  }
}

// ---------------------------------------------------------------------------
// k_hcm: x_hc conv via MFMA. C[wo 128][c 64] per (b,h); K = wi*9taps.
// B from xb16 NCHW (wi contiguous). out xhc bf16 NCHW gated (packed stores).
// grid (128, nb), block 256.
// ---------------------------------------------------------------------------
__global__ __launch_bounds__(256)
void k_hcm(const bf16* __restrict__ xb16, const bf16* __restrict__ wpkhc,
           const float* __restrict__ bias, const bf16* __restrict__ g,
           bf16* __restrict__ xhc){
  int h = blockIdx.x, b = blockIdx.y;
  int tid = threadIdx.x, lane = tid & 63, wv = tid >> 6;
  int nlo = lane & 15, quad = lane >> 4;
  __shared__ bf16 xs[66][128];
  int n0 = wv*16;
  floatx4 acc[8] = {};
  for (int dh = 0; dh < 3; ++dh){
    int gh = h + dh - 1;
    __syncthreads();
    for (int idx = tid; idx < 1056; idx += 256){
      int s = idx >> 4, w8 = (idx & 15)*8;
      int cc = s - 1;
      uint4 v = make_uint4(0,0,0,0);
      if (cc >= 0 && cc < CC && gh >= 0 && gh < TT)
        v = *(const uint4*)(xb16 + (((size_t)b*CC + cc)*TT + gh)*TT + w8);
      *(uint4*)(&xs[s][w8]) = v;
    }
    __syncthreads();
    #pragma unroll
    for (int dc = 0; dc < 3; ++dc){
      int t = dh*3 + dc;
      #pragma unroll
      for (int kk = 0; kk < 4; ++kk){
        short8 bfr = lds8(&xs[n0 + nlo + dc][kk*32 + quad*8]);
        #pragma unroll
        for (int mm = 0; mm < 8; ++mm){
          short8 a = *(const short8*)(const void*)(wpkhc + (((t*4+kk)*8+mm)*64 + lane)*8);
          acc[mm] = __builtin_amdgcn_mfma_f32_16x16x32_bf16(a, bfr, acc[mm], 0,0,0);
        }
      }
    }
  }
  int c = n0 + nlo;
  #pragma unroll
  for (int mm = 0; mm < 8; ++mm){
    int wo0 = mm*16 + quad*4;
    float4 bs = *(const float4*)(bias + wo0);
    float bsa[4] = { bs.x, bs.y, bs.z, bs.w };
    bf16 gg[4];
    *(uint2*)gg = *(const uint2*)(g + ((size_t)b*C3 + 128 + c)*PP + h*TT + wo0);
    bf16 o4[4];
    #pragma unroll
    for (int r = 0; r < 4; ++r){
      float v = acc[mm][r] + bsa[r];
      v = v > 0.f ? v : 0.1f*v;
      o4[r] = f2b(v * b2f(gg[r]));
    }
    *(uint2*)(xhc + ((size_t)b*CC + c)*PP + h*TT + wo0) = *(uint2*)o4;
  }
}

// ---------------------------------------------------------------------------
// k_down: folded down-conv (four 1x1s) + residual -> outh NHWC bf16.
// grid (64, 4, nb), block 256, 16-o register tile.
// ---------------------------------------------------------------------------
__global__ void k_down(const float* __restrict__ x, const bf16* __restrict__ xhw,
                       const bf16* __restrict__ xcw, const bf16* __restrict__ xhc,
                       const float* __restrict__ wcT, const float* __restrict__ bias,
                       bf16* __restrict__ outh){
  int b = blockIdx.z, o0 = blockIdx.y*16;
  int p = blockIdx.x*256 + threadIdx.x;
  float acc[16];
  #pragma unroll
  for (int i=0;i<16;++i) acc[i] = bias[o0+i];
  size_t base = (size_t)b*CC*PP + p;
  for (int k=0;k<64;++k){
    size_t off = base + (size_t)k*PP;
    float xv = x[off], hv = b2f(xhw[off]), cv = b2f(xcw[off]), av = b2f(xhc[off]);
    const float* w0 = wcT + 0*4096 + k*64 + o0;
    const float* w1 = wcT + 1*4096 + k*64 + o0;
    const float* w2 = wcT + 2*4096 + k*64 + o0;
    const float* w3 = wcT + 3*4096 + k*64 + o0;
    #pragma unroll
    for (int i=0;i<16;++i)
      acc[i] += w0[i]*xv + w1[i]*hv + w2[i]*cv + w3[i]*av;
  }
  bf16 o16[16];
  #pragma unroll
  for (int i=0;i<16;++i){
    acc[i] += x[base + (size_t)(o0+i)*PP];
    o16[i] = f2b(acc[i]);
  }
  bf16* dst = outh + ((size_t)b*PP + p)*64 + o0;
  *(uint4*)(dst)     = *(uint4*)(o16);
  *(uint4*)(dst + 8) = *(uint4*)(o16 + 8);
}

// ---------------------------------------------------------------------------
extern "C" void kernel_launch(void* const* d_in, const int* in_sizes, int n_in,
                              void* d_out, int out_size, void* d_ws, size_t ws_size,
                              hipStream_t stream) {
  const float* x      = (const float*)d_in[0];
  const float* w_hwc  = (const float*)d_in[1];
  const float* b_hwc  = (const float*)d_in[2];
  const float* w_dw   = (const float*)d_in[3];
  const float* b_dw   = (const float*)d_in[4];
  const float* w_hw   = (const float*)d_in[5];
  const float* b_hw   = (const float*)d_in[6];
  const float* w_cw   = (const float*)d_in[7];
  const float* b_cw   = (const float*)d_in[8];
  const float* w_hc   = (const float*)d_in[9];
  const float* b_hc   = (const float*)d_in[10];
  const float* w_down = (const float*)d_in[11];
  const float* b_down = (const float*)d_in[12];
  const float* w_l1   = (const float*)d_in[13];
  const float* b_l1   = (const float*)d_in[14];
  const float* w_l2   = (const float*)d_in[15];
  const float* b_l2   = (const float*)d_in[16];
  float* out = (float*)d_out;

  char* ws = (char*)d_ws;
  // ---- meta (prepacked weights), < 1 MB ----
  float* wcT   = (float*)(ws + 0);        // 65,536
  bf16*  wpk1  = (bf16*) (ws + 65536);    // 24,576
  bf16*  wpkhw = (bf16*) (ws + 90112);    // 73,728
  bf16*  wpkl1 = (bf16*) (ws + 163840);   // 73,728
  bf16*  wpkl2 = (bf16*) (ws + 237568);   // 73,728
  bf16*  wpkcw = (bf16*) (ws + 311296);   // 294,912
  bf16*  wpkhc = (bf16*) (ws + 606208);   // 294,912 -> 901,120

  k_wpk<<<576, 256, 0, stream>>>(w_down, w_hc, w_cw, w_hwc, w_hw, w_l1, w_l2,
                                 wcT, wpk1, wpkhw, wpkl1, wpkl2, wpkcw, wpkhc);

  if (ws_size >= 153092096ull) {
    // ---- full-batch path (153 MB) ----
    bf16* g    = (bf16*)(ws + 2097152);     // 50,331,648
    bf16* xh   = (bf16*)(ws + 52428800);    // 16,777,216
    bf16* xW   = (bf16*)(ws + 69206016);    // 16,777,216
    bf16* xb16 = (bf16*)(ws + 85983232);    // 16,777,216
    bf16* xhw  = (bf16*)(ws + 102760448);   // 16,777,216
    bf16* xcw  = (bf16*)(ws + 119537664);   // 16,777,216
    bf16* xhc  = (bf16*)(ws + 136314880);   // 16,777,216 -> 153,092,096
    bf16* th   = (bf16*)(ws + 102760448);   // t half-batch (50.3 MB), aliases xhw..xhc
    bf16* outh = xW;                        // dead after k_cwm
    bf16* o1h  = xh;                        // dead after hw conv

    k_xh<<<dim3(TT, BB), 256, 0, stream>>>(x, xh);
    k_xw<<<dim3(CC, BB), 256, 0, stream>>>(x, xW);
    k_xb<<<8192, 256, 0, stream>>>(x, xb16, BB*CC*PP/4);
    for (int half = 0; half < 2; ++half){
      k_1x1m<<<dim3(TT, 4), 256, 0, stream>>>(xh + (size_t)half*4*PP*64, wpk1, b_hwc, th);
      k_dwv<<<dim3(64, 24, 4), 256, 0, stream>>>(th, w_dw, b_dw, g + (size_t)half*4*C3*PP);
    }
    k_c3x3m<<<dim3(TT, BB), 256, 0, stream>>>(xh, wpkhw, b_hw, g, 0, nullptr, xhw, nullptr, 0);
    k_cwm  <<<dim3(2, CC, BB), 256, 0, stream>>>(xW, wpkcw, b_cw, g, xcw);
    k_hcm  <<<dim3(TT, BB), 256, 0, stream>>>(xb16, wpkhc, b_hc, g, xhc);
    k_down <<<dim3(64, 4, BB), 256, 0, stream>>>(x, xhw, xcw, xhc, wcT, b_down, outh);
    k_c3x3m<<<dim3(TT, BB), 256, 0, stream>>>(outh, wpkl1, b_l1, nullptr, 0, nullptr, o1h, nullptr, 1);
    k_c3x3m<<<dim3(TT, BB), 256, 0, stream>>>(o1h, wpkl2, b_l2, nullptr, 0, x, nullptr, out, 2);
  } else {
    // ---- per-batch path (~34 MB) ----
    char* P = ws + 2097152;
    bf16* t_b   = (bf16*)(P);              //  6,291,456
    bf16* g_b   = (bf16*)(P + 6291456);    //  6,291,456
    bf16* xh_b  = (bf16*)(P + 12582912);   //  2,097,152
    bf16* xW_b  = (bf16*)(P + 14680064);   //  2,097,152
    bf16* xb_b  = (bf16*)(P + 16777216);   //  2,097,152
    bf16* xhw_b = (bf16*)(P + 18874368);   //  2,097,152
    bf16* xcw_b = (bf16*)(P + 20971520);   //  2,097,152
    bf16* xhc_b = (bf16*)(P + 23068672);   //  2,097,152 -> 25,165,824
    bf16* outh_b = xW_b;
    bf16* o1h_b  = xh_b;
    for (int b = 0; b < BB; ++b){
      const float* xb = x + (size_t)b*CC*PP;
      float* outb = out + (size_t)b*CC*PP;
      k_xh<<<dim3(TT, 1), 256, 0, stream>>>(xb, xh_b);
      k_xw<<<dim3(CC, 1), 256, 0, stream>>>(xb, xW_b);
      k_xb<<<1024, 256, 0, stream>>>(xb, xb_b, CC*PP/4);
      k_1x1m<<<dim3(TT, 1), 256, 0, stream>>>(xh_b, wpk1, b_hwc, t_b);
      k_dwv<<<dim3(64, 24, 1), 256, 0, stream>>>(t_b, w_dw, b_dw, g_b);
      k_c3x3m<<<dim3(TT, 1), 256, 0, stream>>>(xh_b, wpkhw, b_hw, g_b, 0, nullptr, xhw_b, nullptr, 0);
      k_cwm  <<<dim3(2, CC, 1), 256, 0, stream>>>(xW_b, wpkcw, b_cw, g_b, xcw_b);
      k_hcm  <<<dim3(TT, 1), 256, 0, stream>>>(xb_b, wpkhc, b_hc, g_b, xhc_b);
      k_down <<<dim3(64, 4, 1), 256, 0, stream>>>(xb, xhw_b, xcw_b, xhc_b, wcT, b_down, outh_b);
      k_c3x3m<<<dim3(TT, 1), 256, 0, stream>>>(outh_b, wpkl1, b_l1, nullptr, 0, nullptr, o1h_b, nullptr, 1);
      k_c3x3m<<<dim3(TT, 1), 256, 0, stream>>>(o1h_b, wpkl2, b_l2, nullptr, 0, xb, nullptr, outb, 2);
    }
  }
}

// Round 8
// 521.808 us; speedup vs baseline: 8.9112x; 1.1356x over previous
//
#include <hip/hip_runtime.h>
#include <hip/hip_bf16.h>

#define BB 8
#define CC 64
#define TT 128
#define PP (TT*TT)
#define C3 192

typedef __hip_bfloat16 bf16;
typedef __attribute__((ext_vector_type(8))) short short8;
typedef __attribute__((ext_vector_type(4))) float floatx4;

__device__ __forceinline__ float b2f(bf16 v){ return __bfloat162float(v); }
__device__ __forceinline__ bf16 f2b(float v){ return __float2bfloat16(v); }
__device__ __forceinline__ short8 lds8(const bf16* p){ return *(const short8*)(const void*)p; }

// ---------------------------------------------------------------------------
// k_wpk: weight prepack into MFMA A-frag lane order.
// A[m][k] frag: m = mm*16 + (lane&15), k = kk*32 + (lane>>4)*8 + j.
// wpkd = folded down-conv weights, K=256 over (s=x,hw,cw,hc)(c).
// ---------------------------------------------------------------------------
__global__ void k_wpk(const float* __restrict__ w_down, const float* __restrict__ w_hc,
                      const float* __restrict__ w_cw,  const float* __restrict__ w_hwc,
                      const float* __restrict__ w_hw,  const float* __restrict__ w_l1,
                      const float* __restrict__ w_l2,
                      bf16* __restrict__ wpkd, bf16* __restrict__ wpk1,
                      bf16* __restrict__ wpkhw, bf16* __restrict__ wpkl1,
                      bf16* __restrict__ wpkl2, bf16* __restrict__ wpkcw,
                      bf16* __restrict__ wpkhc){
  int i = blockIdx.x*256 + threadIdx.x;
  if (i < 147456){   // cw: t=dc*3+dw ; hc: t=dh*3+dc ; M=128,K=128
    int j = i & 7, lane = (i>>3) & 63, mm = (i>>9) & 7, kk = (i>>12) & 3, t = i >> 14;
    int m = mm*16 + (lane & 15);
    int k = kk*32 + (lane>>4)*8 + j;
    wpkcw[i] = f2b(w_cw[m*1152 + k*9 + t]);
    wpkhc[i] = f2b(w_hc[m*1152 + k*9 + t]);
  }
  if (i < 36864){    // hw/l1/l2: M=64,K=64, t=dh*3+dw
    int j = i & 7, lane = (i>>3) & 63, mm = (i>>9) & 3, kk = (i>>11) & 1, t = i >> 12;
    int oc = mm*16 + (lane & 15);
    int ic = kk*32 + (lane>>4)*8 + j;
    int s = oc*576 + ic*9 + t;
    wpkhw[i] = f2b(w_hw[s]);
    wpkl1[i] = f2b(w_l1[s]);
    wpkl2[i] = f2b(w_l2[s]);
  }
  if (i < 12288){    // 1x1: M=192 (mm 0..11), K=64
    int j = i & 7, lane = (i>>3) & 63, rest = i >> 9;
    int mm = rest % 12, kk = rest / 12;
    int oc = mm*16 + (lane & 15);
    int ic = kk*32 + (lane>>4)*8 + j;
    wpk1[((kk*12+mm)*64 + lane)*8 + j] = f2b(w_hwc[oc*64 + ic]);
  }
  if (i < 16384){    // down: M=64, K=256 (kk 0..7), k = s*64+c, w = wd[s]+wd[7-s]
    int j = i & 7, lane = (i>>3) & 63, mm = (i>>9) & 3, kk = i >> 11;  // kk 0..7
    int m = mm*16 + (lane & 15);
    int k = kk*32 + (lane>>4)*8 + j;
    int s = k >> 6, c = k & 63;
    wpkd[i] = f2b(w_down[m*512 + c*8 + s] + w_down[m*512 + c*8 + 7 - s]);
  }
}

// ---------------------------------------------------------------------------
// k_pack: x(fp32 NCHW) -> xh (NHWC bf16) + xb16 (NCHW bf16), one x read.
// grid (TT, nb), block 256.
// ---------------------------------------------------------------------------
__global__ void k_pack(const float* __restrict__ x, bf16* __restrict__ xh,
                       bf16* __restrict__ xb16){
  int h = blockIdx.x, b = blockIdx.y;
  __shared__ float xs[64][129];
  for (int idx = threadIdx.x; idx < 2048; idx += 256){
    int c = idx >> 5, w4 = (idx & 31)*4;
    float4 v = *(const float4*)(x + ((size_t)b*CC + c)*PP + h*TT + w4);
    bf16 o4[4] = { f2b(v.x), f2b(v.y), f2b(v.z), f2b(v.w) };
    *(uint2*)(xb16 + ((size_t)b*CC + c)*PP + h*TT + w4) = *(uint2*)o4;
    xs[c][w4] = v.x; xs[c][w4+1] = v.y; xs[c][w4+2] = v.z; xs[c][w4+3] = v.w;
  }
  __syncthreads();
  for (int idx = threadIdx.x; idx < 8192; idx += 256){
    int w = idx >> 6, c = idx & 63;
    xh[(((size_t)b*TT + h)*TT + w)*64 + c] = f2b(xs[c][w]);
  }
}

// xW = [b][c][w][h] bf16 (for cw conv B-operand, h contiguous)
__global__ void k_xw(const float* __restrict__ x, bf16* __restrict__ xW){
  int c = blockIdx.x, b = blockIdx.y;
  __shared__ float xs2[32][129];
  const float* src = x + ((size_t)b*CC + c)*PP;
  bf16* dst = xW + ((size_t)b*CC + c)*PP;
  for (int s = 0; s < 4; ++s){
    for (int idx = threadIdx.x; idx < 4096; idx += 256){
      int hl = idx >> 7, w = idx & 127;
      xs2[hl][w] = src[(s*32 + hl)*TT + w];
    }
    __syncthreads();
    for (int idx = threadIdx.x; idx < 4096; idx += 256){
      int w = idx >> 5, hl = idx & 31;
      dst[w*TT + s*32 + hl] = f2b(xs2[hl][w]);
    }
    __syncthreads();
  }
}

// ---------------------------------------------------------------------------
// k_1x1m: MFMA 1x1 expand. C[oc 192][w 128] per (b,h). t NHWC bf16 [b][p][192].
// ---------------------------------------------------------------------------
__global__ __launch_bounds__(256)
void k_1x1m(const bf16* __restrict__ xh, const bf16* __restrict__ wpk1,
            const float* __restrict__ bias, bf16* __restrict__ t){
  int h = blockIdx.x, b = blockIdx.y;
  int tid = threadIdx.x, lane = tid & 63, wv = tid >> 6;
  int nlo = lane & 15, quad = lane >> 4;
  __shared__ bf16 xs[128][64];
  for (int idx = tid; idx < 1024; idx += 256){
    int w = idx >> 3, c8 = (idx & 7)*8;
    *(uint4*)(&xs[w][c8]) = *(const uint4*)(xh + (((size_t)b*TT + h)*TT + w)*64 + c8);
  }
  __syncthreads();
  int n0 = wv*32;
  floatx4 acc[12][2] = {};
  #pragma unroll
  for (int kk = 0; kk < 2; ++kk){
    short8 b0 = lds8(&xs[n0 + nlo][kk*32 + quad*8]);
    short8 b1 = lds8(&xs[n0 + 16 + nlo][kk*32 + quad*8]);
    #pragma unroll
    for (int mm = 0; mm < 12; ++mm){
      short8 a = *(const short8*)(const void*)(wpk1 + ((kk*12+mm)*64 + lane)*8);
      acc[mm][0] = __builtin_amdgcn_mfma_f32_16x16x32_bf16(a, b0, acc[mm][0], 0,0,0);
      acc[mm][1] = __builtin_amdgcn_mfma_f32_16x16x32_bf16(a, b1, acc[mm][1], 0,0,0);
    }
  }
  #pragma unroll
  for (int mm = 0; mm < 12; ++mm){
    int oc0 = mm*16 + quad*4;
    float4 bs = *(const float4*)(bias + oc0);
    #pragma unroll
    for (int nn = 0; nn < 2; ++nn){
      int w = n0 + nn*16 + nlo;
      bf16 o4[4] = { f2b(acc[mm][nn][0] + bs.x), f2b(acc[mm][nn][1] + bs.y),
                     f2b(acc[mm][nn][2] + bs.z), f2b(acc[mm][nn][3] + bs.w) };
      *(uint2*)(t + ((size_t)b*PP + h*TT + w)*C3 + oc0) = *(uint2*)o4;
    }
  }
}

// ---------------------------------------------------------------------------
// k_dwv: depthwise 3x3 on t (NHWC bf16) -> g (NCHW bf16).
// ---------------------------------------------------------------------------
__global__ void k_dwv(const bf16* __restrict__ t, const float* __restrict__ w_dw,
                      const float* __restrict__ b_dw, bf16* __restrict__ g){
  int p = blockIdx.x*256 + threadIdx.x;
  int ch0 = blockIdx.y*8, b = blockIdx.z;
  int h = p >> 7, w = p & 127;
  float acc[8];
  #pragma unroll
  for (int i=0;i<8;++i) acc[i] = b_dw[ch0+i];
  #pragma unroll
  for (int dh = 0; dh < 3; ++dh){
    int hh = h + dh - 1;
    if (hh < 0 || hh >= TT) continue;
    #pragma unroll
    for (int dw = 0; dw < 3; ++dw){
      int ww = w + dw - 1;
      if (ww < 0 || ww >= TT) continue;
      bf16 v[8];
      *(uint4*)v = *(const uint4*)(t + ((size_t)b*PP + hh*TT + ww)*C3 + ch0);
      #pragma unroll
      for (int i=0;i<8;++i) acc[i] += w_dw[(ch0+i)*9 + dh*3 + dw] * b2f(v[i]);
    }
  }
  #pragma unroll
  for (int i=0;i<8;++i) g[((size_t)b*C3 + ch0+i)*PP + p] = f2b(acc[i]);
}

// ---------------------------------------------------------------------------
// k_c3x3m: MFMA 64->64 3x3 conv over NHWC bf16 input.
// mode 0: yb NHWC bf16 = lrelu(conv)*g[goff+oc]   (packed stores)
// mode 1: yb NHWC bf16 = lrelu(conv)
// mode 2: yf NCHW fp32 = lrelu(conv) + resx
// ---------------------------------------------------------------------------
__global__ __launch_bounds__(256)
void k_c3x3m(const bf16* __restrict__ in, const bf16* __restrict__ wpk,
             const float* __restrict__ bias, const bf16* __restrict__ g, int goff,
             const float* __restrict__ resx, bf16* __restrict__ yb,
             float* __restrict__ yf, int mode){
  int h = blockIdx.x, b = blockIdx.y;
  int tid = threadIdx.x, lane = tid & 63, wv = tid >> 6;
  int nlo = lane & 15, quad = lane >> 4;
  __shared__ bf16 xs[3][130][64];
  for (int idx = tid; idx < 3120; idx += 256){
    int dh = idx / 1040, r = idx % 1040, wi = r >> 3, c8 = (r & 7)*8;
    int gh = h + dh - 1, gw = wi - 1;
    uint4 v = make_uint4(0,0,0,0);
    if (gh >= 0 && gh < TT && gw >= 0 && gw < TT)
      v = *(const uint4*)(in + (((size_t)b*TT + gh)*TT + gw)*64 + c8);
    *(uint4*)(&xs[dh][wi][c8]) = v;
  }
  __syncthreads();
  int n0 = wv*32;
  floatx4 acc[4][2] = {};
  #pragma unroll
  for (int t = 0; t < 9; ++t){
    int dh = t/3, dw = t%3;
    #pragma unroll
    for (int kk = 0; kk < 2; ++kk){
      short8 b0 = lds8(&xs[dh][n0 + nlo + dw][kk*32 + quad*8]);
      short8 b1 = lds8(&xs[dh][n0 + 16 + nlo + dw][kk*32 + quad*8]);
      #pragma unroll
      for (int mm = 0; mm < 4; ++mm){
        short8 a = *(const short8*)(const void*)(wpk + (((t*2+kk)*4+mm)*64 + lane)*8);
        acc[mm][0] = __builtin_amdgcn_mfma_f32_16x16x32_bf16(a, b0, acc[mm][0], 0,0,0);
        acc[mm][1] = __builtin_amdgcn_mfma_f32_16x16x32_bf16(a, b1, acc[mm][1], 0,0,0);
      }
    }
  }
  #pragma unroll
  for (int mm = 0; mm < 4; ++mm){
    int oc0 = mm*16 + quad*4;
    float4 bs = *(const float4*)(bias + oc0);
    float bsa[4] = { bs.x, bs.y, bs.z, bs.w };
    #pragma unroll
    for (int nn = 0; nn < 2; ++nn){
      int w = n0 + nn*16 + nlo;
      int pi = h*TT + w;
      if (mode == 0){
        bf16 o4[4];
        #pragma unroll
        for (int r = 0; r < 4; ++r){
          float v = acc[mm][nn][r] + bsa[r];
          v = v > 0.f ? v : 0.1f*v;
          v *= b2f(g[((size_t)b*C3 + goff + oc0 + r)*PP + pi]);
          o4[r] = f2b(v);
        }
        *(uint2*)(yb + ((size_t)b*PP + pi)*64 + oc0) = *(uint2*)o4;
      } else if (mode == 1){
        bf16 o4[4];
        #pragma unroll
        for (int r = 0; r < 4; ++r){
          float v = acc[mm][nn][r] + bsa[r];
          o4[r] = f2b(v > 0.f ? v : 0.1f*v);
        }
        *(uint2*)(yb + ((size_t)b*PP + pi)*64 + oc0) = *(uint2*)o4;
      } else {
        #pragma unroll
        for (int r = 0; r < 4; ++r){
          int oc = oc0 + r;
          float v = acc[mm][nn][r] + bsa[r];
          v = v > 0.f ? v : 0.1f*v;
          yf[((size_t)b*CC + oc)*PP + pi] = v + resx[((size_t)b*CC + oc)*PP + pi];
        }
      }
    }
  }
}

// ---------------------------------------------------------------------------
// k_cwm: x_cw conv via MFMA. C[ho 128][w 64] per (half, c, b); out NCHW bf16.
// ---------------------------------------------------------------------------
__global__ __launch_bounds__(256)
void k_cwm(const bf16* __restrict__ xW, const bf16* __restrict__ wpkcw,
           const float* __restrict__ bias, const bf16* __restrict__ g,
           bf16* __restrict__ xcw){
  int w0b = blockIdx.x*64, c = blockIdx.y, b = blockIdx.z;
  int tid = threadIdx.x, lane = tid & 63, wv = tid >> 6;
  int nlo = lane & 15, quad = lane >> 4;
  __shared__ bf16 xs[66][128];
  int nloc = wv*16 + nlo;
  floatx4 acc[8] = {};
  for (int dc = 0; dc < 3; ++dc){
    int cc = c + dc - 1;
    if (cc < 0 || cc >= CC) continue;
    __syncthreads();
    for (int idx = tid; idx < 1056; idx += 256){
      int s = idx >> 4, h8 = (idx & 15)*8;
      int gw = w0b - 1 + s;
      uint4 v = make_uint4(0,0,0,0);
      if (gw >= 0 && gw < TT)
        v = *(const uint4*)(xW + (((size_t)b*CC + cc)*TT + gw)*TT + h8);
      *(uint4*)(&xs[s][h8]) = v;
    }
    __syncthreads();
    #pragma unroll
    for (int dw = 0; dw < 3; ++dw){
      int t = dc*3 + dw;
      #pragma unroll
      for (int kk = 0; kk < 4; ++kk){
        short8 bfr = lds8(&xs[nloc + dw][kk*32 + quad*8]);
        #pragma unroll
        for (int mm = 0; mm < 8; ++mm){
          short8 a = *(const short8*)(const void*)(wpkcw + (((t*4+kk)*8+mm)*64 + lane)*8);
          acc[mm] = __builtin_amdgcn_mfma_f32_16x16x32_bf16(a, bfr, acc[mm], 0,0,0);
        }
      }
    }
  }
  int w = w0b + nloc;
  #pragma unroll
  for (int mm = 0; mm < 8; ++mm){
    int ho0 = mm*16 + quad*4;
    float4 bs = *(const float4*)(bias + ho0);
    float bsa[4] = { bs.x, bs.y, bs.z, bs.w };
    #pragma unroll
    for (int r = 0; r < 4; ++r){
      int ho = ho0 + r;
      float v = acc[mm][r] + bsa[r];
      v = v > 0.f ? v : 0.1f*v;
      v *= b2f(g[((size_t)b*C3 + 64 + c)*PP + ho*TT + w]);
      xcw[((size_t)b*CC + c)*PP + ho*TT + w] = f2b(v);
    }
  }
}

// ---------------------------------------------------------------------------
// k_hcm: x_hc conv via MFMA. C[wo 128][c 64] per (b,h); out NHWC bf16.
// ---------------------------------------------------------------------------
__global__ __launch_bounds__(256)
void k_hcm(const bf16* __restrict__ xb16, const bf16* __restrict__ wpkhc,
           const float* __restrict__ bias, const bf16* __restrict__ g,
           bf16* __restrict__ xhch){
  int h = blockIdx.x, b = blockIdx.y;
  int tid = threadIdx.x, lane = tid & 63, wv = tid >> 6;
  int nlo = lane & 15, quad = lane >> 4;
  __shared__ bf16 xs[66][128];
  int n0 = wv*16;
  floatx4 acc[8] = {};
  for (int dh = 0; dh < 3; ++dh){
    int gh = h + dh - 1;
    __syncthreads();
    for (int idx = tid; idx < 1056; idx += 256){
      int s = idx >> 4, w8 = (idx & 15)*8;
      int cc = s - 1;
      uint4 v = make_uint4(0,0,0,0);
      if (cc >= 0 && cc < CC && gh >= 0 && gh < TT)
        v = *(const uint4*)(xb16 + (((size_t)b*CC + cc)*TT + gh)*TT + w8);
      *(uint4*)(&xs[s][w8]) = v;
    }
    __syncthreads();
    #pragma unroll
    for (int dc = 0; dc < 3; ++dc){
      int t = dh*3 + dc;
      #pragma unroll
      for (int kk = 0; kk < 4; ++kk){
        short8 bfr = lds8(&xs[n0 + nlo + dc][kk*32 + quad*8]);
        #pragma unroll
        for (int mm = 0; mm < 8; ++mm){
          short8 a = *(const short8*)(const void*)(wpkhc + (((t*4+kk)*8+mm)*64 + lane)*8);
          acc[mm] = __builtin_amdgcn_mfma_f32_16x16x32_bf16(a, bfr, acc[mm], 0,0,0);
        }
      }
    }
  }
  int c = n0 + nlo;
  #pragma unroll
  for (int mm = 0; mm < 8; ++mm){
    int wo0 = mm*16 + quad*4;
    float4 bs = *(const float4*)(bias + wo0);
    float bsa[4] = { bs.x, bs.y, bs.z, bs.w };
    bf16 gg[4];
    *(uint2*)gg = *(const uint2*)(g + ((size_t)b*C3 + 128 + c)*PP + h*TT + wo0);
    #pragma unroll
    for (int r = 0; r < 4; ++r){
      int wo = wo0 + r;
      float v = acc[mm][r] + bsa[r];
      v = v > 0.f ? v : 0.1f*v;
      xhch[((size_t)b*PP + h*TT + wo)*64 + c] = f2b(v * b2f(gg[r]));
    }
  }
}

// ---------------------------------------------------------------------------
// k_downm: folded down-conv as MFMA GEMM, K=256 over (x, x_hw, x_cw, x_hc),
// plus residual x. N=128 pixels (one h row), M=64. x_cw (NCHW) is LDS-
// transposed; the NHWC tensors feed B-frags directly. out NHWC bf16.
// grid (TT, nb), block 256.
// ---------------------------------------------------------------------------
__global__ __launch_bounds__(256)
void k_downm(const bf16* __restrict__ xh, const bf16* __restrict__ xhwh,
             const bf16* __restrict__ xcwn, const bf16* __restrict__ xhch,
             const bf16* __restrict__ wpkd, const float* __restrict__ x,
             const float* __restrict__ bias, bf16* __restrict__ outh){
  int h = blockIdx.x, b = blockIdx.y;
  int tid = threadIdx.x, lane = tid & 63, wv = tid >> 6;
  int nlo = lane & 15, quad = lane >> 4;
  int p0 = h*TT;
  __shared__ bf16 xs[128][76];
  for (int idx = tid; idx < 1024; idx += 256){
    int c = idx >> 4, w8 = (idx & 15)*8;
    bf16 tmp[8];
    *(uint4*)tmp = *(const uint4*)(xcwn + ((size_t)b*CC + c)*PP + p0 + w8);
    #pragma unroll
    for (int j = 0; j < 8; ++j) xs[w8+j][c] = tmp[j];
  }
  __syncthreads();
  int n0 = wv*32;
  floatx4 acc[4][2] = {};
  #pragma unroll
  for (int kk = 0; kk < 8; ++kk){
    int s = kk >> 1;
    int ko = (kk & 1)*32 + quad*8;
    short8 bfr[2];
    #pragma unroll
    for (int nn = 0; nn < 2; ++nn){
      int p = n0 + nn*16 + nlo;
      if (s == 2){
        bfr[nn] = lds8(&xs[p][ko]);
      } else {
        const bf16* src = (s == 0) ? xh : (s == 1) ? xhwh : xhch;
        bfr[nn] = *(const short8*)(const void*)(src + ((size_t)b*PP + p0 + p)*64 + ko);
      }
    }
    #pragma unroll
    for (int mm = 0; mm < 4; ++mm){
      short8 a = *(const short8*)(const void*)(wpkd + ((kk*4+mm)*64 + lane)*8);
      acc[mm][0] = __builtin_amdgcn_mfma_f32_16x16x32_bf16(a, bfr[0], acc[mm][0], 0,0,0);
      acc[mm][1] = __builtin_amdgcn_mfma_f32_16x16x32_bf16(a, bfr[1], acc[mm][1], 0,0,0);
    }
  }
  #pragma unroll
  for (int mm = 0; mm < 4; ++mm){
    int o0 = mm*16 + quad*4;
    float4 bs = *(const float4*)(bias + o0);
    float bsa[4] = { bs.x, bs.y, bs.z, bs.w };
    #pragma unroll
    for (int nn = 0; nn < 2; ++nn){
      int p = n0 + nn*16 + nlo;
      bf16 o4[4];
      #pragma unroll
      for (int r = 0; r < 4; ++r){
        float v = acc[mm][nn][r] + bsa[r] + x[((size_t)b*CC + o0 + r)*PP + p0 + p];
        o4[r] = f2b(v);
      }
      *(uint2*)(outh + ((size_t)b*PP + p0 + p)*64 + o0) = *(uint2*)o4;
    }
  }
}

// ---------------------------------------------------------------------------
extern "C" void kernel_launch(void* const* d_in, const int* in_sizes, int n_in,
                              void* d_out, int out_size, void* d_ws, size_t ws_size,
                              hipStream_t stream) {
  const float* x      = (const float*)d_in[0];
  const float* w_hwc  = (const float*)d_in[1];
  const float* b_hwc  = (const float*)d_in[2];
  const float* w_dw   = (const float*)d_in[3];
  const float* b_dw   = (const float*)d_in[4];
  const float* w_hw   = (const float*)d_in[5];
  const float* b_hw   = (const float*)d_in[6];
  const float* w_cw   = (const float*)d_in[7];
  const float* b_cw   = (const float*)d_in[8];
  const float* w_hc   = (const float*)d_in[9];
  const float* b_hc   = (const float*)d_in[10];
  const float* w_down = (const float*)d_in[11];
  const float* b_down = (const float*)d_in[12];
  const float* w_l1   = (const float*)d_in[13];
  const float* b_l1   = (const float*)d_in[14];
  const float* w_l2   = (const float*)d_in[15];
  const float* b_l2   = (const float*)d_in[16];
  float* out = (float*)d_out;

  char* ws = (char*)d_ws;
  // ---- meta (prepacked weights) ----
  bf16*  wpkd  = (bf16*) (ws + 0);        // 32,768 B (16384 elem)
  bf16*  wpk1  = (bf16*) (ws + 65536);    // 24,576
  bf16*  wpkhw = (bf16*) (ws + 90112);    // 73,728
  bf16*  wpkl1 = (bf16*) (ws + 163840);   // 73,728
  bf16*  wpkl2 = (bf16*) (ws + 237568);   // 73,728
  bf16*  wpkcw = (bf16*) (ws + 311296);   // 294,912
  bf16*  wpkhc = (bf16*) (ws + 606208);   // 294,912 -> 901,120

  k_wpk<<<576, 256, 0, stream>>>(w_down, w_hc, w_cw, w_hwc, w_hw, w_l1, w_l2,
                                 wpkd, wpk1, wpkhw, wpkl1, wpkl2, wpkcw, wpkhc);

  if (ws_size >= 153092096ull) {
    // ---- full-batch path (153 MB) ----
    bf16* g    = (bf16*)(ws + 2097152);     // 50,331,648
    bf16* xh   = (bf16*)(ws + 52428800);    // 16,777,216
    bf16* xW   = (bf16*)(ws + 69206016);    // 16,777,216
    bf16* xb16 = (bf16*)(ws + 85983232);    // 16,777,216
    bf16* xhwh = (bf16*)(ws + 102760448);   // 16,777,216 (NHWC)
    bf16* xcw  = (bf16*)(ws + 119537664);   // 16,777,216 (NCHW)
    bf16* xhch = (bf16*)(ws + 136314880);   // 16,777,216 (NHWC) -> 153,092,096
    bf16* th   = (bf16*)(ws + 102760448);   // t half-batch (25.2 MB used), dead before xhwh written
    bf16* outh = xW;                        // dead after k_cwm
    bf16* o1h  = xb16;                      // dead after k_hcm

    k_pack<<<dim3(TT, BB), 256, 0, stream>>>(x, xh, xb16);
    k_xw<<<dim3(CC, BB), 256, 0, stream>>>(x, xW);
    for (int half = 0; half < 2; ++half){
      k_1x1m<<<dim3(TT, 4), 256, 0, stream>>>(xh + (size_t)half*4*PP*64, wpk1, b_hwc, th);
      k_dwv<<<dim3(64, 24, 4), 256, 0, stream>>>(th, w_dw, b_dw, g + (size_t)half*4*C3*PP);
    }
    k_c3x3m<<<dim3(TT, BB), 256, 0, stream>>>(xh, wpkhw, b_hw, g, 0, nullptr, xhwh, nullptr, 0);
    k_cwm  <<<dim3(2, CC, BB), 256, 0, stream>>>(xW, wpkcw, b_cw, g, xcw);
    k_hcm  <<<dim3(TT, BB), 256, 0, stream>>>(xb16, wpkhc, b_hc, g, xhch);
    k_downm<<<dim3(TT, BB), 256, 0, stream>>>(xh, xhwh, xcw, xhch, wpkd, x, b_down, outh);
    k_c3x3m<<<dim3(TT, BB), 256, 0, stream>>>(outh, wpkl1, b_l1, nullptr, 0, nullptr, o1h, nullptr, 1);
    k_c3x3m<<<dim3(TT, BB), 256, 0, stream>>>(o1h, wpkl2, b_l2, nullptr, 0, x, nullptr, out, 2);
  } else {
    // ---- per-batch path (~27 MB) ----
    char* P = ws + 2097152;
    bf16* t_b    = (bf16*)(P);              //  6,291,456
    bf16* g_b    = (bf16*)(P + 6291456);    //  6,291,456
    bf16* xh_b   = (bf16*)(P + 12582912);   //  2,097,152
    bf16* xW_b   = (bf16*)(P + 14680064);   //  2,097,152
    bf16* xb_b   = (bf16*)(P + 16777216);   //  2,097,152
    bf16* xhwh_b = (bf16*)(P + 18874368);   //  2,097,152
    bf16* xcw_b  = (bf16*)(P + 20971520);   //  2,097,152
    bf16* xhch_b = (bf16*)(P + 23068672);   //  2,097,152 -> 25,165,824
    bf16* outh_b = xW_b;
    bf16* o1h_b  = xb_b;
    for (int b = 0; b < BB; ++b){
      const float* xb = x + (size_t)b*CC*PP;
      float* outb = out + (size_t)b*CC*PP;
      k_pack<<<dim3(TT, 1), 256, 0, stream>>>(xb, xh_b, xb_b);
      k_xw<<<dim3(CC, 1), 256, 0, stream>>>(xb, xW_b);
      k_1x1m<<<dim3(TT, 1), 256, 0, stream>>>(xh_b, wpk1, b_hwc, t_b);
      k_dwv<<<dim3(64, 24, 1), 256, 0, stream>>>(t_b, w_dw, b_dw, g_b);
      k_c3x3m<<<dim3(TT, 1), 256, 0, stream>>>(xh_b, wpkhw, b_hw, g_b, 0, nullptr, xhwh_b, nullptr, 0);
      k_cwm  <<<dim3(2, CC, 1), 256, 0, stream>>>(xW_b, wpkcw, b_cw, g_b, xcw_b);
      k_hcm  <<<dim3(TT, 1), 256, 0, stream>>>(xb_b, wpkhc, b_hc, g_b, xhch_b);
      k_downm<<<dim3(TT, 1), 256, 0, stream>>>(xh_b, xhwh_b, xcw_b, xhch_b, wpkd, xb, b_down, outh_b);
      k_c3x3m<<<dim3(TT, 1), 256, 0, stream>>>(outh_b, wpkl1, b_l1, nullptr, 0, nullptr, o1h_b, nullptr, 1);
      k_c3x3m<<<dim3(TT, 1), 256, 0, stream>>>(o1h_b, wpkl2, b_l2, nullptr, 0, xb, nullptr, outb, 2);
    }
  }
}

// Round 9
// 445.377 us; speedup vs baseline: 10.4404x; 1.1716x over previous
//
#include <hip/hip_runtime.h>
#include <hip/hip_bf16.h>

#define BB 8
#define CC 64
#define TT 128
#define PP (TT*TT)
#define C3 192

typedef __hip_bfloat16 bf16;
typedef __attribute__((ext_vector_type(8))) short short8;
typedef __attribute__((ext_vector_type(4))) float floatx4;

__device__ __forceinline__ float b2f(bf16 v){ return __bfloat162float(v); }
__device__ __forceinline__ bf16 f2b(float v){ return __float2bfloat16(v); }
__device__ __forceinline__ short8 lds8(const bf16* p){ return *(const short8*)(const void*)p; }

// ---------------------------------------------------------------------------
// k_wpk: weight prepack into MFMA A-frag lane order.
// A[m][k] frag: m = mm*16 + (lane&15), k = kk*32 + (lane>>4)*8 + j.
// wpkd = folded down-conv weights, K=256 over (s=x,hw,cw,hc)(c).
// ---------------------------------------------------------------------------
__global__ void k_wpk(const float* __restrict__ w_down, const float* __restrict__ w_hc,
                      const float* __restrict__ w_cw,  const float* __restrict__ w_hwc,
                      const float* __restrict__ w_hw,  const float* __restrict__ w_l1,
                      const float* __restrict__ w_l2,
                      bf16* __restrict__ wpkd, bf16* __restrict__ wpk1,
                      bf16* __restrict__ wpkhw, bf16* __restrict__ wpkl1,
                      bf16* __restrict__ wpkl2, bf16* __restrict__ wpkcw,
                      bf16* __restrict__ wpkhc){
  int i = blockIdx.x*256 + threadIdx.x;
  if (i < 147456){   // cw: t=dc*3+dw ; hc: t=dh*3+dc ; M=128,K=128
    int j = i & 7, lane = (i>>3) & 63, mm = (i>>9) & 7, kk = (i>>12) & 3, t = i >> 14;
    int m = mm*16 + (lane & 15);
    int k = kk*32 + (lane>>4)*8 + j;
    wpkcw[i] = f2b(w_cw[m*1152 + k*9 + t]);
    wpkhc[i] = f2b(w_hc[m*1152 + k*9 + t]);
  }
  if (i < 36864){    // hw/l1/l2: M=64,K=64, t=dh*3+dw
    int j = i & 7, lane = (i>>3) & 63, mm = (i>>9) & 3, kk = (i>>11) & 1, t = i >> 12;
    int oc = mm*16 + (lane & 15);
    int ic = kk*32 + (lane>>4)*8 + j;
    int s = oc*576 + ic*9 + t;
    wpkhw[i] = f2b(w_hw[s]);
    wpkl1[i] = f2b(w_l1[s]);
    wpkl2[i] = f2b(w_l2[s]);
  }
  if (i < 12288){    // 1x1: M=192 (mm 0..11), K=64
    int j = i & 7, lane = (i>>3) & 63, rest = i >> 9;
    int mm = rest % 12, kk = rest / 12;
    int oc = mm*16 + (lane & 15);
    int ic = kk*32 + (lane>>4)*8 + j;
    wpk1[((kk*12+mm)*64 + lane)*8 + j] = f2b(w_hwc[oc*64 + ic]);
  }
  if (i < 16384){    // down: M=64, K=256 (kk 0..7), k = s*64+c, w = wd[s]+wd[7-s]
    int j = i & 7, lane = (i>>3) & 63, mm = (i>>9) & 3, kk = i >> 11;  // kk 0..7
    int m = mm*16 + (lane & 15);
    int k = kk*32 + (lane>>4)*8 + j;
    int s = k >> 6, c = k & 63;
    wpkd[i] = f2b(w_down[m*512 + c*8 + s] + w_down[m*512 + c*8 + 7 - s]);
  }
}

// ---------------------------------------------------------------------------
// k_pack: x(fp32 NCHW) -> xh (NHWC bf16) + xb16 (NCHW bf16), one x read.
// ---------------------------------------------------------------------------
__global__ void k_pack(const float* __restrict__ x, bf16* __restrict__ xh,
                       bf16* __restrict__ xb16){
  int h = blockIdx.x, b = blockIdx.y;
  __shared__ float xs[64][129];
  for (int idx = threadIdx.x; idx < 2048; idx += 256){
    int c = idx >> 5, w4 = (idx & 31)*4;
    float4 v = *(const float4*)(x + ((size_t)b*CC + c)*PP + h*TT + w4);
    bf16 o4[4] = { f2b(v.x), f2b(v.y), f2b(v.z), f2b(v.w) };
    *(uint2*)(xb16 + ((size_t)b*CC + c)*PP + h*TT + w4) = *(uint2*)o4;
    xs[c][w4] = v.x; xs[c][w4+1] = v.y; xs[c][w4+2] = v.z; xs[c][w4+3] = v.w;
  }
  __syncthreads();
  for (int idx = threadIdx.x; idx < 8192; idx += 256){
    int w = idx >> 6, c = idx & 63;
    xh[(((size_t)b*TT + h)*TT + w)*64 + c] = f2b(xs[c][w]);
  }
}

// xW = [b][c][w][h] bf16 (for cw conv B-operand, h contiguous)
__global__ void k_xw(const float* __restrict__ x, bf16* __restrict__ xW){
  int c = blockIdx.x, b = blockIdx.y;
  __shared__ float xs2[32][129];
  const float* src = x + ((size_t)b*CC + c)*PP;
  bf16* dst = xW + ((size_t)b*CC + c)*PP;
  for (int s = 0; s < 4; ++s){
    for (int idx = threadIdx.x; idx < 4096; idx += 256){
      int hl = idx >> 7, w = idx & 127;
      xs2[hl][w] = src[(s*32 + hl)*TT + w];
    }
    __syncthreads();
    for (int idx = threadIdx.x; idx < 4096; idx += 256){
      int w = idx >> 5, hl = idx & 31;
      dst[w*TT + s*32 + hl] = f2b(xs2[hl][w]);
    }
    __syncthreads();
  }
}

// ---------------------------------------------------------------------------
// k_1x1m: MFMA 1x1 expand, XOR-swizzled LDS (chunk ^= row&7, 16B units).
// ---------------------------------------------------------------------------
__global__ __launch_bounds__(256)
void k_1x1m(const bf16* __restrict__ xh, const bf16* __restrict__ wpk1,
            const float* __restrict__ bias, bf16* __restrict__ t){
  int h = blockIdx.x, b = blockIdx.y;
  int tid = threadIdx.x, lane = tid & 63, wv = tid >> 6;
  int nlo = lane & 15, quad = lane >> 4;
  __shared__ bf16 xs[128][64];
  for (int idx = tid; idx < 1024; idx += 256){
    int w = idx >> 3, ch = idx & 7;
    *(uint4*)(&xs[w][((ch ^ (w & 7)))*8]) =
      *(const uint4*)(xh + (((size_t)b*TT + h)*TT + w)*64 + ch*8);
  }
  __syncthreads();
  int n0 = wv*32;
  int sw0 = (n0 + nlo) & 7;     // swizzle key (same for both n-chunks: 16 ≡ 0 mod 8)
  floatx4 acc[12][2] = {};
  #pragma unroll
  for (int kk = 0; kk < 2; ++kk){
    int pc = ((kk*4 + quad) ^ sw0)*8;
    short8 b0 = lds8(&xs[n0 + nlo][pc]);
    short8 b1 = lds8(&xs[n0 + 16 + nlo][pc]);
    #pragma unroll
    for (int mm = 0; mm < 12; ++mm){
      short8 a = *(const short8*)(const void*)(wpk1 + ((kk*12+mm)*64 + lane)*8);
      acc[mm][0] = __builtin_amdgcn_mfma_f32_16x16x32_bf16(a, b0, acc[mm][0], 0,0,0);
      acc[mm][1] = __builtin_amdgcn_mfma_f32_16x16x32_bf16(a, b1, acc[mm][1], 0,0,0);
    }
  }
  #pragma unroll
  for (int mm = 0; mm < 12; ++mm){
    int oc0 = mm*16 + quad*4;
    float4 bs = *(const float4*)(bias + oc0);
    #pragma unroll
    for (int nn = 0; nn < 2; ++nn){
      int w = n0 + nn*16 + nlo;
      bf16 o4[4] = { f2b(acc[mm][nn][0] + bs.x), f2b(acc[mm][nn][1] + bs.y),
                     f2b(acc[mm][nn][2] + bs.z), f2b(acc[mm][nn][3] + bs.w) };
      *(uint2*)(t + ((size_t)b*PP + h*TT + w)*C3 + oc0) = *(uint2*)o4;
    }
  }
}

// ---------------------------------------------------------------------------
// k_dwv: depthwise 3x3 on t (NHWC bf16) -> g (NCHW bf16).
// ---------------------------------------------------------------------------
__global__ void k_dwv(const bf16* __restrict__ t, const float* __restrict__ w_dw,
                      const float* __restrict__ b_dw, bf16* __restrict__ g){
  int p = blockIdx.x*256 + threadIdx.x;
  int ch0 = blockIdx.y*8, b = blockIdx.z;
  int h = p >> 7, w = p & 127;
  float acc[8];
  #pragma unroll
  for (int i=0;i<8;++i) acc[i] = b_dw[ch0+i];
  #pragma unroll
  for (int dh = 0; dh < 3; ++dh){
    int hh = h + dh - 1;
    if (hh < 0 || hh >= TT) continue;
    #pragma unroll
    for (int dw = 0; dw < 3; ++dw){
      int ww = w + dw - 1;
      if (ww < 0 || ww >= TT) continue;
      bf16 v[8];
      *(uint4*)v = *(const uint4*)(t + ((size_t)b*PP + hh*TT + ww)*C3 + ch0);
      #pragma unroll
      for (int i=0;i<8;++i) acc[i] += w_dw[(ch0+i)*9 + dh*3 + dw] * b2f(v[i]);
    }
  }
  #pragma unroll
  for (int i=0;i<8;++i) g[((size_t)b*C3 + ch0+i)*PP + p] = f2b(acc[i]);
}

// ---------------------------------------------------------------------------
// k_c3x3m: MFMA 64->64 3x3 conv over NHWC bf16 input. Wave = one 16-oc M
// block (mm = wave id), N = 128; XOR-swizzled LDS. A-loads 18/wave.
// mode 0: yb NHWC = lrelu*gate; 1: yb NHWC = lrelu; 2: yf NCHW fp32 = lrelu+res
// ---------------------------------------------------------------------------
__global__ __launch_bounds__(256)
void k_c3x3m(const bf16* __restrict__ in, const bf16* __restrict__ wpk,
             const float* __restrict__ bias, const bf16* __restrict__ g, int goff,
             const float* __restrict__ resx, bf16* __restrict__ yb,
             float* __restrict__ yf, int mode){
  int h = blockIdx.x, b = blockIdx.y;
  int tid = threadIdx.x, lane = tid & 63, wv = tid >> 6;
  int nlo = lane & 15, quad = lane >> 4;
  __shared__ bf16 xs[3][130][64];
  for (int idx = tid; idx < 3120; idx += 256){
    int dh = idx / 1040, r = idx % 1040, wi = r >> 3, ch = r & 7;
    int gh = h + dh - 1, gw = wi - 1;
    uint4 v = make_uint4(0,0,0,0);
    if (gh >= 0 && gh < TT && gw >= 0 && gw < TT)
      v = *(const uint4*)(in + (((size_t)b*TT + gh)*TT + gw)*64 + ch*8);
    *(uint4*)(&xs[dh][wi][((ch ^ (wi & 7)))*8]) = v;
  }
  __syncthreads();
  floatx4 acc[8] = {};
  #pragma unroll
  for (int t = 0; t < 9; ++t){
    int dh = t/3, dw = t%3;
    int swk = (nlo + dw) & 7;   // row&7, independent of nn (16 ≡ 0 mod 8)
    #pragma unroll
    for (int kk = 0; kk < 2; ++kk){
      short8 a = *(const short8*)(const void*)(wpk + (((t*2+kk)*4+wv)*64 + lane)*8);
      int pc = ((kk*4 + quad) ^ swk)*8;
      #pragma unroll
      for (int nn = 0; nn < 8; ++nn){
        short8 bf = lds8(&xs[dh][nn*16 + nlo + dw][pc]);
        acc[nn] = __builtin_amdgcn_mfma_f32_16x16x32_bf16(a, bf, acc[nn], 0,0,0);
      }
    }
  }
  int oc0 = wv*16 + quad*4;
  float4 bs = *(const float4*)(bias + oc0);
  float bsa[4] = { bs.x, bs.y, bs.z, bs.w };
  #pragma unroll
  for (int nn = 0; nn < 8; ++nn){
    int w = nn*16 + nlo;
    int pi = h*TT + w;
    if (mode == 0){
      bf16 o4[4];
      #pragma unroll
      for (int r = 0; r < 4; ++r){
        float v = acc[nn][r] + bsa[r];
        v = v > 0.f ? v : 0.1f*v;
        v *= b2f(g[((size_t)b*C3 + goff + oc0 + r)*PP + pi]);
        o4[r] = f2b(v);
      }
      *(uint2*)(yb + ((size_t)b*PP + pi)*64 + oc0) = *(uint2*)o4;
    } else if (mode == 1){
      bf16 o4[4];
      #pragma unroll
      for (int r = 0; r < 4; ++r){
        float v = acc[nn][r] + bsa[r];
        o4[r] = f2b(v > 0.f ? v : 0.1f*v);
      }
      *(uint2*)(yb + ((size_t)b*PP + pi)*64 + oc0) = *(uint2*)o4;
    } else {
      #pragma unroll
      for (int r = 0; r < 4; ++r){
        int oc = oc0 + r;
        float v = acc[nn][r] + bsa[r];
        v = v > 0.f ? v : 0.1f*v;
        yf[((size_t)b*CC + oc)*PP + pi] = v + resx[((size_t)b*CC + oc)*PP + pi];
      }
    }
  }
}

// ---------------------------------------------------------------------------
// k_cwm: x_cw conv via MFMA. Wave = two 16-ho M blocks, N = 64 w;
// XOR-swizzled LDS; A-loads 72/wave (was 288). out NCHW bf16 gated.
// grid (2, CC, nb), block 256.
// ---------------------------------------------------------------------------
__global__ __launch_bounds__(256)
void k_cwm(const bf16* __restrict__ xW, const bf16* __restrict__ wpkcw,
           const float* __restrict__ bias, const bf16* __restrict__ g,
           bf16* __restrict__ xcw){
  int w0b = blockIdx.x*64, c = blockIdx.y, b = blockIdx.z;
  int tid = threadIdx.x, lane = tid & 63, wv = tid >> 6;
  int nlo = lane & 15, quad = lane >> 4;
  __shared__ bf16 xs[66][128];
  floatx4 acc[2][4] = {};
  for (int dc = 0; dc < 3; ++dc){
    int cc = c + dc - 1;
    if (cc < 0 || cc >= CC) continue;     // block-uniform
    __syncthreads();
    for (int idx = tid; idx < 1056; idx += 256){
      int s = idx >> 4, ch = idx & 15;
      int gw = w0b - 1 + s;
      uint4 v = make_uint4(0,0,0,0);
      if (gw >= 0 && gw < TT)
        v = *(const uint4*)(xW + (((size_t)b*CC + cc)*TT + gw)*TT + ch*8);
      *(uint4*)(&xs[s][((ch ^ (s & 7)))*8]) = v;
    }
    __syncthreads();
    #pragma unroll
    for (int dw = 0; dw < 3; ++dw){
      int t = dc*3 + dw;
      int swk = (nlo + dw) & 7;
      #pragma unroll
      for (int kk = 0; kk < 4; ++kk){
        short8 a0 = *(const short8*)(const void*)(wpkcw + (((t*4+kk)*8 + wv*2    )*64 + lane)*8);
        short8 a1 = *(const short8*)(const void*)(wpkcw + (((t*4+kk)*8 + wv*2 + 1)*64 + lane)*8);
        int pc = ((kk*4 + quad) ^ swk)*8;
        #pragma unroll
        for (int nn = 0; nn < 4; ++nn){
          short8 bf = lds8(&xs[nn*16 + nlo + dw][pc]);
          acc[0][nn] = __builtin_amdgcn_mfma_f32_16x16x32_bf16(a0, bf, acc[0][nn], 0,0,0);
          acc[1][nn] = __builtin_amdgcn_mfma_f32_16x16x32_bf16(a1, bf, acc[1][nn], 0,0,0);
        }
      }
    }
  }
  #pragma unroll
  for (int ml = 0; ml < 2; ++ml){
    int ho0 = (wv*2 + ml)*16 + quad*4;
    float4 bs = *(const float4*)(bias + ho0);
    float bsa[4] = { bs.x, bs.y, bs.z, bs.w };
    #pragma unroll
    for (int nn = 0; nn < 4; ++nn){
      int w = w0b + nn*16 + nlo;
      #pragma unroll
      for (int r = 0; r < 4; ++r){
        int ho = ho0 + r;
        float v = acc[ml][nn][r] + bsa[r];
        v = v > 0.f ? v : 0.1f*v;
        v *= b2f(g[((size_t)b*C3 + 64 + c)*PP + ho*TT + w]);
        xcw[((size_t)b*CC + c)*PP + ho*TT + w] = f2b(v);
      }
    }
  }
}

// ---------------------------------------------------------------------------
// k_hcm: x_hc conv via MFMA. Wave = two 16-wo M blocks, N = 64 c;
// XOR-swizzled LDS; A-loads 72/wave. out NHWC bf16 gated.
// grid (TT, nb), block 256.
// ---------------------------------------------------------------------------
__global__ __launch_bounds__(256)
void k_hcm(const bf16* __restrict__ xb16, const bf16* __restrict__ wpkhc,
           const float* __restrict__ bias, const bf16* __restrict__ g,
           bf16* __restrict__ xhch){
  int h = blockIdx.x, b = blockIdx.y;
  int tid = threadIdx.x, lane = tid & 63, wv = tid >> 6;
  int nlo = lane & 15, quad = lane >> 4;
  __shared__ bf16 xs[66][128];
  floatx4 acc[2][4] = {};
  for (int dh = 0; dh < 3; ++dh){
    int gh = h + dh - 1;
    __syncthreads();
    for (int idx = tid; idx < 1056; idx += 256){
      int s = idx >> 4, ch = idx & 15;
      int cc = s - 1;
      uint4 v = make_uint4(0,0,0,0);
      if (cc >= 0 && cc < CC && gh >= 0 && gh < TT)
        v = *(const uint4*)(xb16 + (((size_t)b*CC + cc)*TT + gh)*TT + ch*8);
      *(uint4*)(&xs[s][((ch ^ (s & 7)))*8]) = v;
    }
    __syncthreads();
    #pragma unroll
    for (int dc = 0; dc < 3; ++dc){
      int t = dh*3 + dc;
      int swk = (nlo + dc) & 7;
      #pragma unroll
      for (int kk = 0; kk < 4; ++kk){
        short8 a0 = *(const short8*)(const void*)(wpkhc + (((t*4+kk)*8 + wv*2    )*64 + lane)*8);
        short8 a1 = *(const short8*)(const void*)(wpkhc + (((t*4+kk)*8 + wv*2 + 1)*64 + lane)*8);
        int pc = ((kk*4 + quad) ^ swk)*8;
        #pragma unroll
        for (int nn = 0; nn < 4; ++nn){
          short8 bf = lds8(&xs[nn*16 + nlo + dc][pc]);
          acc[0][nn] = __builtin_amdgcn_mfma_f32_16x16x32_bf16(a0, bf, acc[0][nn], 0,0,0);
          acc[1][nn] = __builtin_amdgcn_mfma_f32_16x16x32_bf16(a1, bf, acc[1][nn], 0,0,0);
        }
      }
    }
  }
  #pragma unroll
  for (int ml = 0; ml < 2; ++ml){
    int wo0 = (wv*2 + ml)*16 + quad*4;
    float4 bs = *(const float4*)(bias + wo0);
    float bsa[4] = { bs.x, bs.y, bs.z, bs.w };
    #pragma unroll
    for (int nn = 0; nn < 4; ++nn){
      int c = nn*16 + nlo;
      bf16 gg[4];
      *(uint2*)gg = *(const uint2*)(g + ((size_t)b*C3 + 128 + c)*PP + h*TT + wo0);
      #pragma unroll
      for (int r = 0; r < 4; ++r){
        float v = acc[ml][nn][r] + bsa[r];
        v = v > 0.f ? v : 0.1f*v;
        xhch[((size_t)b*PP + h*TT + wo0 + r)*64 + c] = f2b(v * b2f(gg[r]));
      }
    }
  }
}

// ---------------------------------------------------------------------------
// k_downm: folded down-conv as MFMA GEMM, K=256 over (x, x_hw, x_cw, x_hc),
// plus residual x. out NHWC bf16. grid (TT, nb), block 256.
// ---------------------------------------------------------------------------
__global__ __launch_bounds__(256)
void k_downm(const bf16* __restrict__ xh, const bf16* __restrict__ xhwh,
             const bf16* __restrict__ xcwn, const bf16* __restrict__ xhch,
             const bf16* __restrict__ wpkd, const float* __restrict__ x,
             const float* __restrict__ bias, bf16* __restrict__ outh){
  int h = blockIdx.x, b = blockIdx.y;
  int tid = threadIdx.x, lane = tid & 63, wv = tid >> 6;
  int nlo = lane & 15, quad = lane >> 4;
  int p0 = h*TT;
  __shared__ bf16 xs[128][76];
  for (int idx = tid; idx < 1024; idx += 256){
    int c = idx >> 4, w8 = (idx & 15)*8;
    bf16 tmp[8];
    *(uint4*)tmp = *(const uint4*)(xcwn + ((size_t)b*CC + c)*PP + p0 + w8);
    #pragma unroll
    for (int j = 0; j < 8; ++j) xs[w8+j][c] = tmp[j];
  }
  __syncthreads();
  int n0 = wv*32;
  floatx4 acc[4][2] = {};
  #pragma unroll
  for (int kk = 0; kk < 8; ++kk){
    int s = kk >> 1;
    int ko = (kk & 1)*32 + quad*8;
    short8 bfr[2];
    #pragma unroll
    for (int nn = 0; nn < 2; ++nn){
      int p = n0 + nn*16 + nlo;
      if (s == 2){
        bfr[nn] = lds8(&xs[p][ko]);
      } else {
        const bf16* src = (s == 0) ? xh : (s == 1) ? xhwh : xhch;
        bfr[nn] = *(const short8*)(const void*)(src + ((size_t)b*PP + p0 + p)*64 + ko);
      }
    }
    #pragma unroll
    for (int mm = 0; mm < 4; ++mm){
      short8 a = *(const short8*)(const void*)(wpkd + ((kk*4+mm)*64 + lane)*8);
      acc[mm][0] = __builtin_amdgcn_mfma_f32_16x16x32_bf16(a, bfr[0], acc[mm][0], 0,0,0);
      acc[mm][1] = __builtin_amdgcn_mfma_f32_16x16x32_bf16(a, bfr[1], acc[mm][1], 0,0,0);
    }
  }
  #pragma unroll
  for (int mm = 0; mm < 4; ++mm){
    int o0 = mm*16 + quad*4;
    float4 bs = *(const float4*)(bias + o0);
    float bsa[4] = { bs.x, bs.y, bs.z, bs.w };
    #pragma unroll
    for (int nn = 0; nn < 2; ++nn){
      int p = n0 + nn*16 + nlo;
      bf16 o4[4];
      #pragma unroll
      for (int r = 0; r < 4; ++r){
        float v = acc[mm][nn][r] + bsa[r] + x[((size_t)b*CC + o0 + r)*PP + p0 + p];
        o4[r] = f2b(v);
      }
      *(uint2*)(outh + ((size_t)b*PP + p0 + p)*64 + o0) = *(uint2*)o4;
    }
  }
}

// ---------------------------------------------------------------------------
extern "C" void kernel_launch(void* const* d_in, const int* in_sizes, int n_in,
                              void* d_out, int out_size, void* d_ws, size_t ws_size,
                              hipStream_t stream) {
  const float* x      = (const float*)d_in[0];
  const float* w_hwc  = (const float*)d_in[1];
  const float* b_hwc  = (const float*)d_in[2];
  const float* w_dw   = (const float*)d_in[3];
  const float* b_dw   = (const float*)d_in[4];
  const float* w_hw   = (const float*)d_in[5];
  const float* b_hw   = (const float*)d_in[6];
  const float* w_cw   = (const float*)d_in[7];
  const float* b_cw   = (const float*)d_in[8];
  const float* w_hc   = (const float*)d_in[9];
  const float* b_hc   = (const float*)d_in[10];
  const float* w_down = (const float*)d_in[11];
  const float* b_down = (const float*)d_in[12];
  const float* w_l1   = (const float*)d_in[13];
  const float* b_l1   = (const float*)d_in[14];
  const float* w_l2   = (const float*)d_in[15];
  const float* b_l2   = (const float*)d_in[16];
  float* out = (float*)d_out;

  char* ws = (char*)d_ws;
  // ---- meta (prepacked weights) ----
  bf16*  wpkd  = (bf16*) (ws + 0);        // 32,768 B
  bf16*  wpk1  = (bf16*) (ws + 65536);    // 24,576
  bf16*  wpkhw = (bf16*) (ws + 90112);    // 73,728
  bf16*  wpkl1 = (bf16*) (ws + 163840);   // 73,728
  bf16*  wpkl2 = (bf16*) (ws + 237568);   // 73,728
  bf16*  wpkcw = (bf16*) (ws + 311296);   // 294,912
  bf16*  wpkhc = (bf16*) (ws + 606208);   // 294,912 -> 901,120

  k_wpk<<<576, 256, 0, stream>>>(w_down, w_hc, w_cw, w_hwc, w_hw, w_l1, w_l2,
                                 wpkd, wpk1, wpkhw, wpkl1, wpkl2, wpkcw, wpkhc);

  if (ws_size >= 153092096ull) {
    // ---- full-batch path (153 MB) ----
    bf16* g    = (bf16*)(ws + 2097152);     // 50,331,648
    bf16* xh   = (bf16*)(ws + 52428800);    // 16,777,216
    bf16* xW   = (bf16*)(ws + 69206016);    // 16,777,216
    bf16* xb16 = (bf16*)(ws + 85983232);    // 16,777,216
    bf16* xhwh = (bf16*)(ws + 102760448);   // 16,777,216 (NHWC)
    bf16* xcw  = (bf16*)(ws + 119537664);   // 16,777,216 (NCHW)
    bf16* xhch = (bf16*)(ws + 136314880);   // 16,777,216 (NHWC) -> 153,092,096
    bf16* th   = (bf16*)(ws + 102760448);   // t half-batch, dead before xhwh written
    bf16* outh = xW;                        // dead after k_cwm
    bf16* o1h  = xb16;                      // dead after k_hcm

    k_pack<<<dim3(TT, BB), 256, 0, stream>>>(x, xh, xb16);
    k_xw<<<dim3(CC, BB), 256, 0, stream>>>(x, xW);
    for (int half = 0; half < 2; ++half){
      k_1x1m<<<dim3(TT, 4), 256, 0, stream>>>(xh + (size_t)half*4*PP*64, wpk1, b_hwc, th);
      k_dwv<<<dim3(64, 24, 4), 256, 0, stream>>>(th, w_dw, b_dw, g + (size_t)half*4*C3*PP);
    }
    k_c3x3m<<<dim3(TT, BB), 256, 0, stream>>>(xh, wpkhw, b_hw, g, 0, nullptr, xhwh, nullptr, 0);
    k_cwm  <<<dim3(2, CC, BB), 256, 0, stream>>>(xW, wpkcw, b_cw, g, xcw);
    k_hcm  <<<dim3(TT, BB), 256, 0, stream>>>(xb16, wpkhc, b_hc, g, xhch);
    k_downm<<<dim3(TT, BB), 256, 0, stream>>>(xh, xhwh, xcw, xhch, wpkd, x, b_down, outh);
    k_c3x3m<<<dim3(TT, BB), 256, 0, stream>>>(outh, wpkl1, b_l1, nullptr, 0, nullptr, o1h, nullptr, 1);
    k_c3x3m<<<dim3(TT, BB), 256, 0, stream>>>(o1h, wpkl2, b_l2, nullptr, 0, x, nullptr, out, 2);
  } else {
    // ---- per-batch path (~27 MB) ----
    char* P = ws + 2097152;
    bf16* t_b    = (bf16*)(P);              //  6,291,456
    bf16* g_b    = (bf16*)(P + 6291456);    //  6,291,456
    bf16* xh_b   = (bf16*)(P + 12582912);   //  2,097,152
    bf16* xW_b   = (bf16*)(P + 14680064);   //  2,097,152
    bf16* xb_b   = (bf16*)(P + 16777216);   //  2,097,152
    bf16* xhwh_b = (bf16*)(P + 18874368);   //  2,097,152
    bf16* xcw_b  = (bf16*)(P + 20971520);   //  2,097,152
    bf16* xhch_b = (bf16*)(P + 23068672);   //  2,097,152 -> 25,165,824
    bf16* outh_b = xW_b;
    bf16* o1h_b  = xb_b;
    for (int b = 0; b < BB; ++b){
      const float* xb = x + (size_t)b*CC*PP;
      float* outb = out + (size_t)b*CC*PP;
      k_pack<<<dim3(TT, 1), 256, 0, stream>>>(xb, xh_b, xb_b);
      k_xw<<<dim3(CC, 1), 256, 0, stream>>>(xb, xW_b);
      k_1x1m<<<dim3(TT, 1), 256, 0, stream>>>(xh_b, wpk1, b_hwc, t_b);
      k_dwv<<<dim3(64, 24, 1), 256, 0, stream>>>(t_b, w_dw, b_dw, g_b);
      k_c3x3m<<<dim3(TT, 1), 256, 0, stream>>>(xh_b, wpkhw, b_hw, g_b, 0, nullptr, xhwh_b, nullptr, 0);
      k_cwm  <<<dim3(2, CC, 1), 256, 0, stream>>>(xW_b, wpkcw, b_cw, g_b, xcw_b);
      k_hcm  <<<dim3(TT, 1), 256, 0, stream>>>(xb_b, wpkhc, b_hc, g_b, xhch_b);
      k_downm<<<dim3(TT, 1), 256, 0, stream>>>(xh_b, xhwh_b, xcw_b, xhch_b, wpkd, xb, b_down, outh_b);
      k_c3x3m<<<dim3(TT, 1), 256, 0, stream>>>(outh_b, wpkl1, b_l1, nullptr, 0, nullptr, o1h_b, nullptr, 1);
      k_c3x3m<<<dim3(TT, 1), 256, 0, stream>>>(o1h_b, wpkl2, b_l2, nullptr, 0, xb, nullptr, outb, 2);
    }
  }
}

// Round 10
// 399.081 us; speedup vs baseline: 11.6516x; 1.1160x over previous
//
#include <hip/hip_runtime.h>
#include <hip/hip_bf16.h>

#define BB 8
#define CC 64
#define TT 128
#define PP (TT*TT)
#define C3 192

typedef __hip_bfloat16 bf16;
typedef __attribute__((ext_vector_type(8))) short short8;
typedef __attribute__((ext_vector_type(4))) float floatx4;

__device__ __forceinline__ float b2f(bf16 v){ return __bfloat162float(v); }
__device__ __forceinline__ bf16 f2b(float v){ return __float2bfloat16(v); }
__device__ __forceinline__ short8 lds8(const bf16* p){ return *(const short8*)(const void*)p; }

// ---------------------------------------------------------------------------
// k_wpk: weight prepack into MFMA A-frag lane order.
// A[m][k] frag: m = mm*16 + (lane&15), k = kk*32 + (lane>>4)*8 + j.
// wpkd = folded down-conv weights, K=256 over (s=x,hw,cw,hc)(c).
// ---------------------------------------------------------------------------
__global__ void k_wpk(const float* __restrict__ w_down, const float* __restrict__ w_hc,
                      const float* __restrict__ w_cw,  const float* __restrict__ w_hwc,
                      const float* __restrict__ w_hw,  const float* __restrict__ w_l1,
                      const float* __restrict__ w_l2,
                      bf16* __restrict__ wpkd, bf16* __restrict__ wpk1,
                      bf16* __restrict__ wpkhw, bf16* __restrict__ wpkl1,
                      bf16* __restrict__ wpkl2, bf16* __restrict__ wpkcw,
                      bf16* __restrict__ wpkhc){
  int i = blockIdx.x*256 + threadIdx.x;
  if (i < 147456){   // cw: t=dc*3+dw ; hc: t=dh*3+dc ; M=128,K=128
    int j = i & 7, lane = (i>>3) & 63, mm = (i>>9) & 7, kk = (i>>12) & 3, t = i >> 14;
    int m = mm*16 + (lane & 15);
    int k = kk*32 + (lane>>4)*8 + j;
    wpkcw[i] = f2b(w_cw[m*1152 + k*9 + t]);
    wpkhc[i] = f2b(w_hc[m*1152 + k*9 + t]);
  }
  if (i < 36864){    // hw/l1/l2: M=64,K=64, t=dh*3+dw
    int j = i & 7, lane = (i>>3) & 63, mm = (i>>9) & 3, kk = (i>>11) & 1, t = i >> 12;
    int oc = mm*16 + (lane & 15);
    int ic = kk*32 + (lane>>4)*8 + j;
    int s = oc*576 + ic*9 + t;
    wpkhw[i] = f2b(w_hw[s]);
    wpkl1[i] = f2b(w_l1[s]);
    wpkl2[i] = f2b(w_l2[s]);
  }
  if (i < 12288){    // 1x1: M=192 (mm 0..11), K=64
    int j = i & 7, lane = (i>>3) & 63, rest = i >> 9;
    int mm = rest % 12, kk = rest / 12;
    int oc = mm*16 + (lane & 15);
    int ic = kk*32 + (lane>>4)*8 + j;
    wpk1[((kk*12+mm)*64 + lane)*8 + j] = f2b(w_hwc[oc*64 + ic]);
  }
  if (i < 16384){    // down: M=64, K=256 (kk 0..7), k = s*64+c, w = wd[s]+wd[7-s]
    int j = i & 7, lane = (i>>3) & 63, mm = (i>>9) & 3, kk = i >> 11;  // kk 0..7
    int m = mm*16 + (lane & 15);
    int k = kk*32 + (lane>>4)*8 + j;
    int s = k >> 6, c = k & 63;
    wpkd[i] = f2b(w_down[m*512 + c*8 + s] + w_down[m*512 + c*8 + 7 - s]);
  }
}

// ---------------------------------------------------------------------------
// k_pack: x(fp32 NCHW) -> xh (NHWC bf16) + xb16 (NCHW bf16), one x read.
// ---------------------------------------------------------------------------
__global__ void k_pack(const float* __restrict__ x, bf16* __restrict__ xh,
                       bf16* __restrict__ xb16){
  int h = blockIdx.x, b = blockIdx.y;
  __shared__ float xs[64][129];
  for (int idx = threadIdx.x; idx < 2048; idx += 256){
    int c = idx >> 5, w4 = (idx & 31)*4;
    float4 v = *(const float4*)(x + ((size_t)b*CC + c)*PP + h*TT + w4);
    bf16 o4[4] = { f2b(v.x), f2b(v.y), f2b(v.z), f2b(v.w) };
    *(uint2*)(xb16 + ((size_t)b*CC + c)*PP + h*TT + w4) = *(uint2*)o4;
    xs[c][w4] = v.x; xs[c][w4+1] = v.y; xs[c][w4+2] = v.z; xs[c][w4+3] = v.w;
  }
  __syncthreads();
  for (int idx = threadIdx.x; idx < 8192; idx += 256){
    int w = idx >> 6, c = idx & 63;
    xh[(((size_t)b*TT + h)*TT + w)*64 + c] = f2b(xs[c][w]);
  }
}

// xW = [b][c][w][h] bf16 (for cw conv B-operand, h contiguous)
__global__ void k_xw(const float* __restrict__ x, bf16* __restrict__ xW){
  int c = blockIdx.x, b = blockIdx.y;
  __shared__ float xs2[32][129];
  const float* src = x + ((size_t)b*CC + c)*PP;
  bf16* dst = xW + ((size_t)b*CC + c)*PP;
  for (int s = 0; s < 4; ++s){
    for (int idx = threadIdx.x; idx < 4096; idx += 256){
      int hl = idx >> 7, w = idx & 127;
      xs2[hl][w] = src[(s*32 + hl)*TT + w];
    }
    __syncthreads();
    for (int idx = threadIdx.x; idx < 4096; idx += 256){
      int w = idx >> 5, hl = idx & 31;
      dst[w*TT + s*32 + hl] = f2b(xs2[hl][w]);
    }
    __syncthreads();
  }
}

// ---------------------------------------------------------------------------
// k_1x1m: MFMA 1x1 expand, XOR-swizzled LDS. t layout: [s=oc/64][b][p][64],
// NB = batches in this launch (t channel-tile batch stride = NB*PP*64).
// ---------------------------------------------------------------------------
__global__ __launch_bounds__(256)
void k_1x1m(const bf16* __restrict__ xh, const bf16* __restrict__ wpk1,
            const float* __restrict__ bias, bf16* __restrict__ t, int NB){
  int h = blockIdx.x, b = blockIdx.y;
  int tid = threadIdx.x, lane = tid & 63, wv = tid >> 6;
  int nlo = lane & 15, quad = lane >> 4;
  __shared__ bf16 xs[128][64];
  for (int idx = tid; idx < 1024; idx += 256){
    int w = idx >> 3, ch = idx & 7;
    *(uint4*)(&xs[w][((ch ^ (w & 7)))*8]) =
      *(const uint4*)(xh + (((size_t)b*TT + h)*TT + w)*64 + ch*8);
  }
  __syncthreads();
  int n0 = wv*32;
  int sw0 = (n0 + nlo) & 7;
  floatx4 acc[12][2] = {};
  #pragma unroll
  for (int kk = 0; kk < 2; ++kk){
    int pc = ((kk*4 + quad) ^ sw0)*8;
    short8 b0 = lds8(&xs[n0 + nlo][pc]);
    short8 b1 = lds8(&xs[n0 + 16 + nlo][pc]);
    #pragma unroll
    for (int mm = 0; mm < 12; ++mm){
      short8 a = *(const short8*)(const void*)(wpk1 + ((kk*12+mm)*64 + lane)*8);
      acc[mm][0] = __builtin_amdgcn_mfma_f32_16x16x32_bf16(a, b0, acc[mm][0], 0,0,0);
      acc[mm][1] = __builtin_amdgcn_mfma_f32_16x16x32_bf16(a, b1, acc[mm][1], 0,0,0);
    }
  }
  #pragma unroll
  for (int mm = 0; mm < 12; ++mm){
    int oc0 = mm*16 + quad*4;
    int s = oc0 >> 6, c = oc0 & 63;
    float4 bs = *(const float4*)(bias + oc0);
    #pragma unroll
    for (int nn = 0; nn < 2; ++nn){
      int w = n0 + nn*16 + nlo;
      bf16 o4[4] = { f2b(acc[mm][nn][0] + bs.x), f2b(acc[mm][nn][1] + bs.y),
                     f2b(acc[mm][nn][2] + bs.z), f2b(acc[mm][nn][3] + bs.w) };
      *(uint2*)(t + (((size_t)s*NB + b)*PP + h*TT + w)*64 + c) = *(uint2*)o4;
    }
  }
}

// ---------------------------------------------------------------------------
// k_dwv2: depthwise 3x3 on t ([s][b][p][64] bf16) -> g (NCHW bf16).
// Block = one (b,h) row; 3 ch-tiles of 64. Stage 3 rows x 128 px x 64 ch in
// LDS (48 KB, XOR-swizzled). Compute: lane = px (coalesced g stores, bank-
// balanced LDS reads), ch8 wave-uniform (weights on scalar pipe).
// grid (TT, NB), block 256.
// ---------------------------------------------------------------------------
__global__ __launch_bounds__(256)
void k_dwv2(const bf16* __restrict__ t, const float* __restrict__ w_dw,
            const float* __restrict__ b_dw, bf16* __restrict__ g, int NB){
  int h = blockIdx.x, b = blockIdx.y;
  int tid = threadIdx.x;
  __shared__ bf16 xs[3][128][64];
  for (int s = 0; s < 3; ++s){
    if (s) __syncthreads();
    for (int idx = tid; idx < 3072; idx += 256){
      int dh = idx >> 10, r = idx & 1023, px = r >> 3, ch = r & 7;
      int gh = h + dh - 1;
      uint4 v = make_uint4(0,0,0,0);
      if (gh >= 0 && gh < TT)
        v = *(const uint4*)(t + (((size_t)s*NB + b)*PP + gh*TT + px)*64 + ch*8);
      *(uint4*)(&xs[dh][px][((ch ^ (px & 7)))*8]) = v;
    }
    __syncthreads();
    #pragma unroll
    for (int it = 0; it < 4; ++it){
      int idx = it*256 + tid;
      int ch8 = idx >> 7, px = idx & 127;   // ch8 is wave-uniform
      int chb = s*64 + ch8*8;
      float acc[8];
      #pragma unroll
      for (int j=0;j<8;++j) acc[j] = b_dw[chb+j];
      #pragma unroll
      for (int dh = 0; dh < 3; ++dh){
        #pragma unroll
        for (int dw = 0; dw < 3; ++dw){
          int pw = px + dw - 1;
          if (pw < 0 || pw >= TT) continue;   // edge lanes only
          short8 xv = lds8(&xs[dh][pw][((ch8 ^ (pw & 7)))*8]);
          #pragma unroll
          for (int j=0;j<8;++j)
            acc[j] += w_dw[(chb+j)*9 + dh*3 + dw] * b2f(((bf16*)&xv)[j]);
        }
      }
      #pragma unroll
      for (int j=0;j<8;++j)
        g[((size_t)b*C3 + chb + j)*PP + h*TT + px] = f2b(acc[j]);
    }
  }
}

// ---------------------------------------------------------------------------
// k_c3x3m: MFMA 64->64 3x3 conv over NHWC bf16 input. Wave = one 16-oc M
// block, N = 128; XOR-swizzled LDS.
// mode 0: yb NHWC = lrelu*gate; 1: yb NHWC = lrelu; 2: yf NCHW fp32 = lrelu+res
// ---------------------------------------------------------------------------
__global__ __launch_bounds__(256)
void k_c3x3m(const bf16* __restrict__ in, const bf16* __restrict__ wpk,
             const float* __restrict__ bias, const bf16* __restrict__ g, int goff,
             const float* __restrict__ resx, bf16* __restrict__ yb,
             float* __restrict__ yf, int mode){
  int h = blockIdx.x, b = blockIdx.y;
  int tid = threadIdx.x, lane = tid & 63, wv = tid >> 6;
  int nlo = lane & 15, quad = lane >> 4;
  __shared__ bf16 xs[3][130][64];
  for (int idx = tid; idx < 3120; idx += 256){
    int dh = idx / 1040, r = idx % 1040, wi = r >> 3, ch = r & 7;
    int gh = h + dh - 1, gw = wi - 1;
    uint4 v = make_uint4(0,0,0,0);
    if (gh >= 0 && gh < TT && gw >= 0 && gw < TT)
      v = *(const uint4*)(in + (((size_t)b*TT + gh)*TT + gw)*64 + ch*8);
    *(uint4*)(&xs[dh][wi][((ch ^ (wi & 7)))*8]) = v;
  }
  __syncthreads();
  floatx4 acc[8] = {};
  #pragma unroll
  for (int t = 0; t < 9; ++t){
    int dh = t/3, dw = t%3;
    int swk = (nlo + dw) & 7;
    #pragma unroll
    for (int kk = 0; kk < 2; ++kk){
      short8 a = *(const short8*)(const void*)(wpk + (((t*2+kk)*4+wv)*64 + lane)*8);
      int pc = ((kk*4 + quad) ^ swk)*8;
      #pragma unroll
      for (int nn = 0; nn < 8; ++nn){
        short8 bf = lds8(&xs[dh][nn*16 + nlo + dw][pc]);
        acc[nn] = __builtin_amdgcn_mfma_f32_16x16x32_bf16(a, bf, acc[nn], 0,0,0);
      }
    }
  }
  int oc0 = wv*16 + quad*4;
  float4 bs = *(const float4*)(bias + oc0);
  float bsa[4] = { bs.x, bs.y, bs.z, bs.w };
  #pragma unroll
  for (int nn = 0; nn < 8; ++nn){
    int w = nn*16 + nlo;
    int pi = h*TT + w;
    if (mode == 0){
      bf16 o4[4];
      #pragma unroll
      for (int r = 0; r < 4; ++r){
        float v = acc[nn][r] + bsa[r];
        v = v > 0.f ? v : 0.1f*v;
        v *= b2f(g[((size_t)b*C3 + goff + oc0 + r)*PP + pi]);
        o4[r] = f2b(v);
      }
      *(uint2*)(yb + ((size_t)b*PP + pi)*64 + oc0) = *(uint2*)o4;
    } else if (mode == 1){
      bf16 o4[4];
      #pragma unroll
      for (int r = 0; r < 4; ++r){
        float v = acc[nn][r] + bsa[r];
        o4[r] = f2b(v > 0.f ? v : 0.1f*v);
      }
      *(uint2*)(yb + ((size_t)b*PP + pi)*64 + oc0) = *(uint2*)o4;
    } else {
      #pragma unroll
      for (int r = 0; r < 4; ++r){
        int oc = oc0 + r;
        float v = acc[nn][r] + bsa[r];
        v = v > 0.f ? v : 0.1f*v;
        yf[((size_t)b*CC + oc)*PP + pi] = v + resx[((size_t)b*CC + oc)*PP + pi];
      }
    }
  }
}

// ---------------------------------------------------------------------------
// k_cwm: x_cw conv via MFMA. Wave = two 16-ho M blocks, N = 64 w;
// XOR-swizzled LDS. out NCHW bf16 gated. grid (2, CC, nb), block 256.
// ---------------------------------------------------------------------------
__global__ __launch_bounds__(256)
void k_cwm(const bf16* __restrict__ xW, const bf16* __restrict__ wpkcw,
           const float* __restrict__ bias, const bf16* __restrict__ g,
           bf16* __restrict__ xcw){
  int w0b = blockIdx.x*64, c = blockIdx.y, b = blockIdx.z;
  int tid = threadIdx.x, lane = tid & 63, wv = tid >> 6;
  int nlo = lane & 15, quad = lane >> 4;
  __shared__ bf16 xs[66][128];
  floatx4 acc[2][4] = {};
  for (int dc = 0; dc < 3; ++dc){
    int cc = c + dc - 1;
    if (cc < 0 || cc >= CC) continue;
    __syncthreads();
    for (int idx = tid; idx < 1056; idx += 256){
      int s = idx >> 4, ch = idx & 15;
      int gw = w0b - 1 + s;
      uint4 v = make_uint4(0,0,0,0);
      if (gw >= 0 && gw < TT)
        v = *(const uint4*)(xW + (((size_t)b*CC + cc)*TT + gw)*TT + ch*8);
      *(uint4*)(&xs[s][((ch ^ (s & 7)))*8]) = v;
    }
    __syncthreads();
    #pragma unroll
    for (int dw = 0; dw < 3; ++dw){
      int t = dc*3 + dw;
      int swk = (nlo + dw) & 7;
      #pragma unroll
      for (int kk = 0; kk < 4; ++kk){
        short8 a0 = *(const short8*)(const void*)(wpkcw + (((t*4+kk)*8 + wv*2    )*64 + lane)*8);
        short8 a1 = *(const short8*)(const void*)(wpkcw + (((t*4+kk)*8 + wv*2 + 1)*64 + lane)*8);
        int pc = ((kk*4 + quad) ^ swk)*8;
        #pragma unroll
        for (int nn = 0; nn < 4; ++nn){
          short8 bf = lds8(&xs[nn*16 + nlo + dw][pc]);
          acc[0][nn] = __builtin_amdgcn_mfma_f32_16x16x32_bf16(a0, bf, acc[0][nn], 0,0,0);
          acc[1][nn] = __builtin_amdgcn_mfma_f32_16x16x32_bf16(a1, bf, acc[1][nn], 0,0,0);
        }
      }
    }
  }
  #pragma unroll
  for (int ml = 0; ml < 2; ++ml){
    int ho0 = (wv*2 + ml)*16 + quad*4;
    float4 bs = *(const float4*)(bias + ho0);
    float bsa[4] = { bs.x, bs.y, bs.z, bs.w };
    #pragma unroll
    for (int nn = 0; nn < 4; ++nn){
      int w = w0b + nn*16 + nlo;
      #pragma unroll
      for (int r = 0; r < 4; ++r){
        int ho = ho0 + r;
        float v = acc[ml][nn][r] + bsa[r];
        v = v > 0.f ? v : 0.1f*v;
        v *= b2f(g[((size_t)b*C3 + 64 + c)*PP + ho*TT + w]);
        xcw[((size_t)b*CC + c)*PP + ho*TT + w] = f2b(v);
      }
    }
  }
}

// ---------------------------------------------------------------------------
// k_hcm: x_hc conv via MFMA. Wave = two 16-wo M blocks, N = 64 c;
// XOR-swizzled LDS. out NHWC bf16 gated. grid (TT, nb), block 256.
// ---------------------------------------------------------------------------
__global__ __launch_bounds__(256)
void k_hcm(const bf16* __restrict__ xb16, const bf16* __restrict__ wpkhc,
           const float* __restrict__ bias, const bf16* __restrict__ g,
           bf16* __restrict__ xhch){
  int h = blockIdx.x, b = blockIdx.y;
  int tid = threadIdx.x, lane = tid & 63, wv = tid >> 6;
  int nlo = lane & 15, quad = lane >> 4;
  __shared__ bf16 xs[66][128];
  floatx4 acc[2][4] = {};
  for (int dh = 0; dh < 3; ++dh){
    int gh = h + dh - 1;
    __syncthreads();
    for (int idx = tid; idx < 1056; idx += 256){
      int s = idx >> 4, ch = idx & 15;
      int cc = s - 1;
      uint4 v = make_uint4(0,0,0,0);
      if (cc >= 0 && cc < CC && gh >= 0 && gh < TT)
        v = *(const uint4*)(xb16 + (((size_t)b*CC + cc)*TT + gh)*TT + ch*8);
      *(uint4*)(&xs[s][((ch ^ (s & 7)))*8]) = v;
    }
    __syncthreads();
    #pragma unroll
    for (int dc = 0; dc < 3; ++dc){
      int t = dh*3 + dc;
      int swk = (nlo + dc) & 7;
      #pragma unroll
      for (int kk = 0; kk < 4; ++kk){
        short8 a0 = *(const short8*)(const void*)(wpkhc + (((t*4+kk)*8 + wv*2    )*64 + lane)*8);
        short8 a1 = *(const short8*)(const void*)(wpkhc + (((t*4+kk)*8 + wv*2 + 1)*64 + lane)*8);
        int pc = ((kk*4 + quad) ^ swk)*8;
        #pragma unroll
        for (int nn = 0; nn < 4; ++nn){
          short8 bf = lds8(&xs[nn*16 + nlo + dc][pc]);
          acc[0][nn] = __builtin_amdgcn_mfma_f32_16x16x32_bf16(a0, bf, acc[0][nn], 0,0,0);
          acc[1][nn] = __builtin_amdgcn_mfma_f32_16x16x32_bf16(a1, bf, acc[1][nn], 0,0,0);
        }
      }
    }
  }
  #pragma unroll
  for (int ml = 0; ml < 2; ++ml){
    int wo0 = (wv*2 + ml)*16 + quad*4;
    float4 bs = *(const float4*)(bias + wo0);
    float bsa[4] = { bs.x, bs.y, bs.z, bs.w };
    #pragma unroll
    for (int nn = 0; nn < 4; ++nn){
      int c = nn*16 + nlo;
      bf16 gg[4];
      *(uint2*)gg = *(const uint2*)(g + ((size_t)b*C3 + 128 + c)*PP + h*TT + wo0);
      #pragma unroll
      for (int r = 0; r < 4; ++r){
        float v = acc[ml][nn][r] + bsa[r];
        v = v > 0.f ? v : 0.1f*v;
        xhch[((size_t)b*PP + h*TT + wo0 + r)*64 + c] = f2b(v * b2f(gg[r]));
      }
    }
  }
}

// ---------------------------------------------------------------------------
// k_downm: folded down-conv as MFMA GEMM, K=256 over (x, x_hw, x_cw, x_hc),
// plus residual x. out NHWC bf16. grid (TT, nb), block 256.
// ---------------------------------------------------------------------------
__global__ __launch_bounds__(256)
void k_downm(const bf16* __restrict__ xh, const bf16* __restrict__ xhwh,
             const bf16* __restrict__ xcwn, const bf16* __restrict__ xhch,
             const bf16* __restrict__ wpkd, const float* __restrict__ x,
             const float* __restrict__ bias, bf16* __restrict__ outh){
  int h = blockIdx.x, b = blockIdx.y;
  int tid = threadIdx.x, lane = tid & 63, wv = tid >> 6;
  int nlo = lane & 15, quad = lane >> 4;
  int p0 = h*TT;
  __shared__ bf16 xs[128][76];
  for (int idx = tid; idx < 1024; idx += 256){
    int c = idx >> 4, w8 = (idx & 15)*8;
    bf16 tmp[8];
    *(uint4*)tmp = *(const uint4*)(xcwn + ((size_t)b*CC + c)*PP + p0 + w8);
    #pragma unroll
    for (int j = 0; j < 8; ++j) xs[w8+j][c] = tmp[j];
  }
  __syncthreads();
  int n0 = wv*32;
  floatx4 acc[4][2] = {};
  #pragma unroll
  for (int kk = 0; kk < 8; ++kk){
    int s = kk >> 1;
    int ko = (kk & 1)*32 + quad*8;
    short8 bfr[2];
    #pragma unroll
    for (int nn = 0; nn < 2; ++nn){
      int p = n0 + nn*16 + nlo;
      if (s == 2){
        bfr[nn] = lds8(&xs[p][ko]);
      } else {
        const bf16* src = (s == 0) ? xh : (s == 1) ? xhwh : xhch;
        bfr[nn] = *(const short8*)(const void*)(src + ((size_t)b*PP + p0 + p)*64 + ko);
      }
    }
    #pragma unroll
    for (int mm = 0; mm < 4; ++mm){
      short8 a = *(const short8*)(const void*)(wpkd + ((kk*4+mm)*64 + lane)*8);
      acc[mm][0] = __builtin_amdgcn_mfma_f32_16x16x32_bf16(a, bfr[0], acc[mm][0], 0,0,0);
      acc[mm][1] = __builtin_amdgcn_mfma_f32_16x16x32_bf16(a, bfr[1], acc[mm][1], 0,0,0);
    }
  }
  #pragma unroll
  for (int mm = 0; mm < 4; ++mm){
    int o0 = mm*16 + quad*4;
    float4 bs = *(const float4*)(bias + o0);
    float bsa[4] = { bs.x, bs.y, bs.z, bs.w };
    #pragma unroll
    for (int nn = 0; nn < 2; ++nn){
      int p = n0 + nn*16 + nlo;
      bf16 o4[4];
      #pragma unroll
      for (int r = 0; r < 4; ++r){
        float v = acc[mm][nn][r] + bsa[r] + x[((size_t)b*CC + o0 + r)*PP + p0 + p];
        o4[r] = f2b(v);
      }
      *(uint2*)(outh + ((size_t)b*PP + p0 + p)*64 + o0) = *(uint2*)o4;
    }
  }
}

// ---------------------------------------------------------------------------
extern "C" void kernel_launch(void* const* d_in, const int* in_sizes, int n_in,
                              void* d_out, int out_size, void* d_ws, size_t ws_size,
                              hipStream_t stream) {
  const float* x      = (const float*)d_in[0];
  const float* w_hwc  = (const float*)d_in[1];
  const float* b_hwc  = (const float*)d_in[2];
  const float* w_dw   = (const float*)d_in[3];
  const float* b_dw   = (const float*)d_in[4];
  const float* w_hw   = (const float*)d_in[5];
  const float* b_hw   = (const float*)d_in[6];
  const float* w_cw   = (const float*)d_in[7];
  const float* b_cw   = (const float*)d_in[8];
  const float* w_hc   = (const float*)d_in[9];
  const float* b_hc   = (const float*)d_in[10];
  const float* w_down = (const float*)d_in[11];
  const float* b_down = (const float*)d_in[12];
  const float* w_l1   = (const float*)d_in[13];
  const float* b_l1   = (const float*)d_in[14];
  const float* w_l2   = (const float*)d_in[15];
  const float* b_l2   = (const float*)d_in[16];
  float* out = (float*)d_out;

  char* ws = (char*)d_ws;
  // ---- meta (prepacked weights) ----
  bf16*  wpkd  = (bf16*) (ws + 0);        // 32,768 B
  bf16*  wpk1  = (bf16*) (ws + 65536);    // 24,576
  bf16*  wpkhw = (bf16*) (ws + 90112);    // 73,728
  bf16*  wpkl1 = (bf16*) (ws + 163840);   // 73,728
  bf16*  wpkl2 = (bf16*) (ws + 237568);   // 73,728
  bf16*  wpkcw = (bf16*) (ws + 311296);   // 294,912
  bf16*  wpkhc = (bf16*) (ws + 606208);   // 294,912 -> 901,120

  k_wpk<<<576, 256, 0, stream>>>(w_down, w_hc, w_cw, w_hwc, w_hw, w_l1, w_l2,
                                 wpkd, wpk1, wpkhw, wpkl1, wpkl2, wpkcw, wpkhc);

  if (ws_size >= 153092096ull) {
    // ---- full-batch path (153 MB) ----
    bf16* g    = (bf16*)(ws + 2097152);     // 50,331,648
    bf16* xh   = (bf16*)(ws + 52428800);    // 16,777,216
    bf16* xW   = (bf16*)(ws + 69206016);    // 16,777,216
    bf16* xb16 = (bf16*)(ws + 85983232);    // 16,777,216
    bf16* xhwh = (bf16*)(ws + 102760448);   // 16,777,216 (NHWC)
    bf16* xcw  = (bf16*)(ws + 119537664);   // 16,777,216 (NCHW)
    bf16* xhch = (bf16*)(ws + 136314880);   // 16,777,216 (NHWC) -> 153,092,096
    bf16* th   = (bf16*)(ws + 102760448);   // t half-batch (25.2 MB), dead before xhwh written
    bf16* outh = xW;                        // dead after k_cwm
    bf16* o1h  = xb16;                      // dead after k_hcm

    k_pack<<<dim3(TT, BB), 256, 0, stream>>>(x, xh, xb16);
    k_xw<<<dim3(CC, BB), 256, 0, stream>>>(x, xW);
    for (int half = 0; half < 2; ++half){
      k_1x1m<<<dim3(TT, 4), 256, 0, stream>>>(xh + (size_t)half*4*PP*64, wpk1, b_hwc, th, 4);
      k_dwv2<<<dim3(TT, 4), 256, 0, stream>>>(th, w_dw, b_dw, g + (size_t)half*4*C3*PP, 4);
    }
    k_c3x3m<<<dim3(TT, BB), 256, 0, stream>>>(xh, wpkhw, b_hw, g, 0, nullptr, xhwh, nullptr, 0);
    k_cwm  <<<dim3(2, CC, BB), 256, 0, stream>>>(xW, wpkcw, b_cw, g, xcw);
    k_hcm  <<<dim3(TT, BB), 256, 0, stream>>>(xb16, wpkhc, b_hc, g, xhch);
    k_downm<<<dim3(TT, BB), 256, 0, stream>>>(xh, xhwh, xcw, xhch, wpkd, x, b_down, outh);
    k_c3x3m<<<dim3(TT, BB), 256, 0, stream>>>(outh, wpkl1, b_l1, nullptr, 0, nullptr, o1h, nullptr, 1);
    k_c3x3m<<<dim3(TT, BB), 256, 0, stream>>>(o1h, wpkl2, b_l2, nullptr, 0, x, nullptr, out, 2);
  } else {
    // ---- per-batch path (~27 MB) ----
    char* P = ws + 2097152;
    bf16* t_b    = (bf16*)(P);              //  6,291,456
    bf16* g_b    = (bf16*)(P + 6291456);    //  6,291,456
    bf16* xh_b   = (bf16*)(P + 12582912);   //  2,097,152
    bf16* xW_b   = (bf16*)(P + 14680064);   //  2,097,152
    bf16* xb_b   = (bf16*)(P + 16777216);   //  2,097,152
    bf16* xhwh_b = (bf16*)(P + 18874368);   //  2,097,152
    bf16* xcw_b  = (bf16*)(P + 20971520);   //  2,097,152
    bf16* xhch_b = (bf16*)(P + 23068672);   //  2,097,152 -> 25,165,824
    bf16* outh_b = xW_b;
    bf16* o1h_b  = xb_b;
    for (int b = 0; b < BB; ++b){
      const float* xb = x + (size_t)b*CC*PP;
      float* outb = out + (size_t)b*CC*PP;
      k_pack<<<dim3(TT, 1), 256, 0, stream>>>(xb, xh_b, xb_b);
      k_xw<<<dim3(CC, 1), 256, 0, stream>>>(xb, xW_b);
      k_1x1m<<<dim3(TT, 1), 256, 0, stream>>>(xh_b, wpk1, b_hwc, t_b, 1);
      k_dwv2<<<dim3(TT, 1), 256, 0, stream>>>(t_b, w_dw, b_dw, g_b, 1);
      k_c3x3m<<<dim3(TT, 1), 256, 0, stream>>>(xh_b, wpkhw, b_hw, g_b, 0, nullptr, xhwh_b, nullptr, 0);
      k_cwm  <<<dim3(2, CC, 1), 256, 0, stream>>>(xW_b, wpkcw, b_cw, g_b, xcw_b);
      k_hcm  <<<dim3(TT, 1), 256, 0, stream>>>(xb_b, wpkhc, b_hc, g_b, xhch_b);
      k_downm<<<dim3(TT, 1), 256, 0, stream>>>(xh_b, xhwh_b, xcw_b, xhch_b, wpkd, xb, b_down, outh_b);
      k_c3x3m<<<dim3(TT, 1), 256, 0, stream>>>(outh_b, wpkl1, b_l1, nullptr, 0, nullptr, o1h_b, nullptr, 1);
      k_c3x3m<<<dim3(TT, 1), 256, 0, stream>>>(o1h_b, wpkl2, b_l2, nullptr, 0, xb, nullptr, outb, 2);
    }
  }
}